// Round 6
// baseline (973.546 us; speedup 1.0000x reference)
//
#include <hip/hip_runtime.h>

#define Nn 50000
#define En 800000
#define NSLOT 64

typedef __attribute__((ext_vector_type(8))) short short8;
typedef __attribute__((ext_vector_type(4))) float f32x4;

union U8 { uint4 u4; unsigned short us[8]; short8 s8; };

static __device__ __forceinline__ float bf2f(unsigned int lo16) {
  return __uint_as_float(lo16 << 16);
}
static __device__ __forceinline__ unsigned short f2bf(float f) {
  unsigned int x = __float_as_uint(f);
  return (unsigned short)((x + 0x7FFFu + ((x >> 16) & 1u)) >> 16);
}

// ---------------- prep kernels ----------------

__global__ __launch_bounds__(256) void k_prep_h(const float* __restrict__ h,
                                                unsigned short* __restrict__ nodeA) {
  int idx = blockIdx.x * 256 + threadIdx.x;
  if (idx >= Nn * 128) return;
  int n = idx >> 7, k = idx & 127;
  nodeA[(size_t)n * 256 + k] = f2bf(h[idx]);
}

// weight fp32 [128][Ksrc] cols [koff, koff+2^kshift) -> bf16 [128][2^kshift]
__global__ __launch_bounds__(256) void k_prep_w(const float* __restrict__ src,
                                                unsigned short* __restrict__ dst, int Ksrc,
                                                int koff, int kshift, int total) {
  int idx = blockIdx.x * 256 + threadIdx.x;
  if (idx >= total) return;
  int n = idx >> kshift;
  int k = idx & ((1 << kshift) - 1);
  dst[idx] = f2bf(src[n * Ksrc + koff + k]);
}

__global__ void k_wlast(const float* __restrict__ e_w1, float* __restrict__ wlast) {
  int t = threadIdx.x;
  if (t < 128) wlast[t] = e_w1[t * 257 + 256];
}

// ---------------- CSR build (edges sorted by row; node ids fit u16) ----------------

__global__ __launch_bounds__(256) void k_count(const int* __restrict__ row, int* __restrict__ cnt) {
  int e = blockIdx.x * 256 + threadIdx.x;
  atomicAdd(&cnt[row[e]], 1);
}

__global__ __launch_bounds__(256) void k_fill(const int* __restrict__ row,
                                              const int* __restrict__ col,
                                              int* __restrict__ cursor,
                                              unsigned short* __restrict__ rowS,
                                              unsigned short* __restrict__ colS) {
  int e = blockIdx.x * 256 + threadIdx.x;
  int r = row[e];
  int pos = atomicAdd(&cursor[r], 1);
  rowS[pos] = (unsigned short)r;
  colS[pos] = (unsigned short)col[e];
}

__global__ __launch_bounds__(1024) void k_scan(const int* __restrict__ cnt, int* __restrict__ start,
                                               int* __restrict__ cursor, int n) {
  __shared__ int wsum[16];
  __shared__ int carry;
  int tid = threadIdx.x, lane = tid & 63, wid = tid >> 6;
  if (tid == 0) carry = 0;
  __syncthreads();
  for (int base = 0; base < n; base += 1024) {
    int i = base + tid;
    int v = (i < n) ? cnt[i] : 0;
    int x = v;
#pragma unroll
    for (int d = 1; d < 64; d <<= 1) {
      int y = __shfl_up(x, d, 64);
      if (lane >= d) x += y;
    }
    if (lane == 63) wsum[wid] = x;
    __syncthreads();
    if (wid == 0) {
      int s = (lane < 16) ? wsum[lane] : 0;
#pragma unroll
      for (int d = 1; d < 16; d <<= 1) {
        int y = __shfl_up(s, d, 64);
        if (lane >= d) s += y;
      }
      if (lane < 16) wsum[lane] = s;
    }
    __syncthreads();
    int c0 = carry;
    int waveoff = (wid > 0) ? wsum[wid - 1] : 0;
    int incl = c0 + waveoff + x;
    if (i < n) {
      start[i] = incl - v;
      cursor[i] = incl - v;
    }
    __syncthreads();
    if (tid == 1023) carry = incl;
    __syncthreads();
  }
}

// ---------------- BN finalize ----------------

__global__ void k_fin(const float* __restrict__ statS, const float* __restrict__ statQ,
                      const float* __restrict__ g, const float* __restrict__ be, float invR,
                      float* __restrict__ bnS, float* __restrict__ bnSh) {
  int c = threadIdx.x;
  if (c >= 128) return;
  float s = 0.f, q = 0.f;
  for (int k = 0; k < NSLOT; ++k) {
    s += statS[k * 128 + c];
    q += statQ[k * 128 + c];
  }
  float mean = s * invR;
  float var = fmaxf(q * invR - mean * mean, 0.f);
  float rs = rsqrtf(var + 1e-5f);
  float sc = g[c] * rs;
  bnS[c] = sc;
  bnSh[c] = be[c] - mean * sc;
}

// ---------------- generic MFMA GEMM with W in LDS ----------------
template <int KSTEPS, bool BN_A, bool STATS, bool FP32OUT, bool STORE>
__global__ __launch_bounds__(256) void k_gemmW(
    const unsigned short* __restrict__ A, int Astride,
    const unsigned short* __restrict__ W, const float* __restrict__ bias,
    const float* __restrict__ bnS, const float* __restrict__ bnSh,
    unsigned short* __restrict__ outb, float* __restrict__ statS, float* __restrict__ statQ,
    const float* __restrict__ hres, float* __restrict__ outf, int R) {
  constexpr int K = KSTEPS * 32;
  constexpr int WST = K + 8;
  constexpr int SEGS = K / 8;
  __shared__ __align__(16) unsigned short smem[128 * WST];
  __shared__ float ssum[4][128], ssq[4][128];
  int tid = threadIdx.x;
  int w = tid >> 6, lane = tid & 63, m = lane & 15, kq = lane >> 4;
  int rbase = blockIdx.x * 128;
#pragma unroll
  for (int it = 0; it < SEGS / 2; ++it) {
    int idx = it * 256 + tid;
    int n = idx / SEGS, seg = idx % SEGS;
    uint4 v = *(const uint4*)(W + (size_t)n * K + seg * 8);
    *(uint4*)(smem + n * WST + seg * 8) = v;
  }
  __syncthreads();
  int row0 = rbase + w * 32 + m;
  int rc0 = min(row0, R - 1);
  int rc1 = min(row0 + 16, R - 1);
  f32x4 acc[2][8];
#pragma unroll
  for (int rt = 0; rt < 2; ++rt)
#pragma unroll
    for (int c = 0; c < 8; ++c) acc[rt][c] = (f32x4){0.f, 0.f, 0.f, 0.f};
#pragma unroll
  for (int ks = 0; ks < KSTEPS; ++ks) {
    int k0 = ks * 32 + kq * 8;
    U8 ua0, ua1;
    ua0.u4 = *(const uint4*)(A + (size_t)rc0 * Astride + k0);
    ua1.u4 = *(const uint4*)(A + (size_t)rc1 * Astride + k0);
    if (BN_A) {
      const float4* sp = (const float4*)(bnS + k0);
      const float4* hp = (const float4*)(bnSh + k0);
      float4 s0 = sp[0], s1 = sp[1], h0 = hp[0], h1 = hp[1];
      float sv[8] = {s0.x, s0.y, s0.z, s0.w, s1.x, s1.y, s1.z, s1.w};
      float hv[8] = {h0.x, h0.y, h0.z, h0.w, h1.x, h1.y, h1.z, h1.w};
#pragma unroll
      for (int j = 0; j < 8; ++j) {
        ua0.us[j] = f2bf(fmaxf(bf2f(ua0.us[j]) * sv[j] + hv[j], 0.f));
        ua1.us[j] = f2bf(fmaxf(bf2f(ua1.us[j]) * sv[j] + hv[j], 0.f));
      }
    }
#pragma unroll
    for (int c = 0; c < 8; ++c) {
      U8 ub;
      ub.u4 = *(const uint4*)(smem + (c * 16 + m) * WST + k0);
      acc[0][c] = __builtin_amdgcn_mfma_f32_16x16x32_bf16(ua0.s8, ub.s8, acc[0][c], 0, 0, 0);
      acc[1][c] = __builtin_amdgcn_mfma_f32_16x16x32_bf16(ua1.s8, ub.s8, acc[1][c], 0, 0, 0);
    }
  }
  if constexpr (FP32OUT) {
#pragma unroll
    for (int rt = 0; rt < 2; ++rt)
#pragma unroll
      for (int c = 0; c < 8; ++c) {
        int n = c * 16 + m;
        float bn_ = bias[n];
#pragma unroll
        for (int j = 0; j < 4; ++j) {
          int rr = rbase + w * 32 + rt * 16 + kq * 4 + j;
          if (rr < R) {
            size_t o = (size_t)rr * 128 + n;
            outf[o] = acc[rt][c][j] + bn_ + hres[o];
          }
        }
      }
  } else {
    if constexpr (STORE) __syncthreads();
    unsigned short* tile = smem;  // reuse as [128][136]
#pragma unroll
    for (int c = 0; c < 8; ++c) {
      int n = c * 16 + m;
      float bn_ = bias ? bias[n] : 0.f;
      float s = 0.f, q = 0.f;
#pragma unroll
      for (int rt = 0; rt < 2; ++rt)
#pragma unroll
        for (int j = 0; j < 4; ++j) {
          int lr = w * 32 + rt * 16 + kq * 4 + j;
          float v = acc[rt][c][j] + bn_;
          if (STORE) tile[lr * 136 + n] = f2bf(v);
          if (STATS) {
            float sv = (rbase + lr < R) ? v : 0.f;
            s += sv;
            q = fmaf(sv, sv, q);
          }
        }
      if (STATS) {
        s += __shfl_xor(s, 16, 64); s += __shfl_xor(s, 32, 64);
        q += __shfl_xor(q, 16, 64); q += __shfl_xor(q, 32, 64);
        if (kq == 0) { ssum[w][n] = s; ssq[w][n] = q; }
      }
    }
    if constexpr (STORE) {
      __syncthreads();
      const uint4* tl = (const uint4*)tile;
#pragma unroll
      for (int u = 0; u < 8; ++u) {
        int idx = u * 256 + tid;
        int rr = idx >> 4, seg = idx & 15;
        if (rbase + rr < R)
          *(uint4*)(outb + (size_t)(rbase + rr) * 128 + seg * 8) = tl[rr * 17 + seg];
      }
    }
    if (STATS) {
      __syncthreads();
      if (tid < 128) {
        float s = ssum[0][tid] + ssum[1][tid] + ssum[2][tid] + ssum[3][tid];
        float q = ssq[0][tid] + ssq[1][tid] + ssq[2][tid] + ssq[3][tid];
        int slot = blockIdx.x & (NSLOT - 1);
        atomicAdd(&statS[slot * 128 + tid], s);
        atomicAdd(&statQ[slot * 128 + tid], q);
      }
    }
  }
}

// ---------------- bn1 stats over virtual t1 (no materialization) + radS ----------------
__global__ __launch_bounds__(256) void k_stats1(
    const unsigned short* __restrict__ hWr, const unsigned short* __restrict__ hWc,
    const float* __restrict__ coord, const unsigned short* __restrict__ rowS,
    const unsigned short* __restrict__ colS, const float* __restrict__ wlast,
    float* __restrict__ radS, float* __restrict__ statS, float* __restrict__ statQ,
    int per_wave) {
  int tid = threadIdx.x, lane = tid & 63;
  int wid = blockIdx.x * 4 + (tid >> 6);
  int e0 = wid * per_wave;
  int e1 = min(e0 + per_wave, En);
  int c2 = lane * 2;
  float wl0 = wlast[c2], wl1 = wlast[c2 + 1];
  float s0 = 0.f, s1 = 0.f, q0 = 0.f, q1 = 0.f;
  for (int e = e0; e < e1; ++e) {
    int r = rowS[e], c = colS[e];
    float dx = coord[r * 3 + 0] - coord[c * 3 + 0];
    float dy = coord[r * 3 + 1] - coord[c * 3 + 1];
    float dz = coord[r * 3 + 2] - coord[c * 3 + 2];
    float rad = dx * dx + dy * dy + dz * dz;
    if (lane == 0) radS[e] = rad;
    unsigned int ua = *(const unsigned int*)(hWr + (size_t)r * 128 + c2);
    unsigned int ub = *(const unsigned int*)(hWc + (size_t)c * 128 + c2);
    float v0 = bf2f(ua & 0xFFFFu) + bf2f(ub & 0xFFFFu) + rad * wl0;
    float v1 = bf2f(ua >> 16) + bf2f(ub >> 16) + rad * wl1;
    s0 += v0; q0 = fmaf(v0, v0, q0);
    s1 += v1; q1 = fmaf(v1, v1, q1);
  }
  int slot = wid & (NSLOT - 1);
  atomicAdd(&statS[slot * 128 + c2], s0);
  atomicAdd(&statS[slot * 128 + c2 + 1], s1);
  atomicAdd(&statQ[slot * 128 + c2], q0);
  atomicAdd(&statQ[slot * 128 + c2 + 1], q1);
}

// ---------------- edge layer 2 GEMM, A recomputed from hWr/hWc/radS ----------------
__global__ __launch_bounds__(256) void k_egemm2(
    const unsigned short* __restrict__ hWr, const unsigned short* __restrict__ hWc,
    const float* __restrict__ radS, const unsigned short* __restrict__ rowS,
    const unsigned short* __restrict__ colS, const unsigned short* __restrict__ W,
    const float* __restrict__ bias, const float* __restrict__ wlast,
    const float* __restrict__ bnS1, const float* __restrict__ bnSh1,
    unsigned short* __restrict__ outb, float* __restrict__ statS, float* __restrict__ statQ) {
  constexpr int WST = 136;
  __shared__ __align__(16) unsigned short smem[128 * WST];
  __shared__ float ssum[4][128], ssq[4][128];
  int tid = threadIdx.x;
  int w = tid >> 6, lane = tid & 63, m = lane & 15, kq = lane >> 4;
  int rbase = blockIdx.x * 128;
#pragma unroll
  for (int it = 0; it < 8; ++it) {
    int idx = it * 256 + tid;
    int n = idx >> 4, seg = idx & 15;
    uint4 v = *(const uint4*)(W + (size_t)n * 128 + seg * 8);
    *(uint4*)(smem + n * WST + seg * 8) = v;
  }
  int rc0 = rbase + w * 32 + m, rc1 = rc0 + 16;
  int r0 = rowS[rc0], c0 = colS[rc0];
  int r1 = rowS[rc1], c1 = colS[rc1];
  float rad0 = radS[rc0], rad1 = radS[rc1];
  __syncthreads();
  f32x4 acc[2][8];
#pragma unroll
  for (int rt = 0; rt < 2; ++rt)
#pragma unroll
    for (int c = 0; c < 8; ++c) acc[rt][c] = (f32x4){0.f, 0.f, 0.f, 0.f};
#pragma unroll
  for (int ks = 0; ks < 4; ++ks) {
    int k0 = ks * 32 + kq * 8;
    U8 a0r, a0c, a1r, a1c;
    a0r.u4 = *(const uint4*)(hWr + (size_t)r0 * 128 + k0);
    a0c.u4 = *(const uint4*)(hWc + (size_t)c0 * 128 + k0);
    a1r.u4 = *(const uint4*)(hWr + (size_t)r1 * 128 + k0);
    a1c.u4 = *(const uint4*)(hWc + (size_t)c1 * 128 + k0);
    const float4* wp = (const float4*)(wlast + k0);
    const float4* sp = (const float4*)(bnS1 + k0);
    const float4* hp = (const float4*)(bnSh1 + k0);
    float4 w0 = wp[0], w1 = wp[1], sA = sp[0], sB = sp[1], hA = hp[0], hB = hp[1];
    float wv[8] = {w0.x, w0.y, w0.z, w0.w, w1.x, w1.y, w1.z, w1.w};
    float sv[8] = {sA.x, sA.y, sA.z, sA.w, sB.x, sB.y, sB.z, sB.w};
    float hv[8] = {hA.x, hA.y, hA.z, hA.w, hB.x, hB.y, hB.z, hB.w};
    U8 ua0, ua1;
#pragma unroll
    for (int j = 0; j < 8; ++j) {
      float v0 = bf2f(a0r.us[j]) + bf2f(a0c.us[j]) + rad0 * wv[j];
      float v1 = bf2f(a1r.us[j]) + bf2f(a1c.us[j]) + rad1 * wv[j];
      ua0.us[j] = f2bf(fmaxf(v0 * sv[j] + hv[j], 0.f));
      ua1.us[j] = f2bf(fmaxf(v1 * sv[j] + hv[j], 0.f));
    }
#pragma unroll
    for (int c = 0; c < 8; ++c) {
      U8 ub;
      ub.u4 = *(const uint4*)(smem + (c * 16 + m) * WST + k0);
      acc[0][c] = __builtin_amdgcn_mfma_f32_16x16x32_bf16(ua0.s8, ub.s8, acc[0][c], 0, 0, 0);
      acc[1][c] = __builtin_amdgcn_mfma_f32_16x16x32_bf16(ua1.s8, ub.s8, acc[1][c], 0, 0, 0);
    }
  }
  __syncthreads();
  unsigned short* tile = smem;
#pragma unroll
  for (int c = 0; c < 8; ++c) {
    int n = c * 16 + m;
    float bn_ = bias[n];
    float s = 0.f, q = 0.f;
#pragma unroll
    for (int rt = 0; rt < 2; ++rt)
#pragma unroll
      for (int j = 0; j < 4; ++j) {
        int lr = w * 32 + rt * 16 + kq * 4 + j;
        float v = acc[rt][c][j] + bn_;
        tile[lr * 136 + n] = f2bf(v);
        s += v;
        q = fmaf(v, v, q);
      }
    s += __shfl_xor(s, 16, 64); s += __shfl_xor(s, 32, 64);
    q += __shfl_xor(q, 16, 64); q += __shfl_xor(q, 32, 64);
    if (kq == 0) { ssum[w][n] = s; ssq[w][n] = q; }
  }
  __syncthreads();
  const uint4* tl = (const uint4*)tile;
#pragma unroll
  for (int u = 0; u < 8; ++u) {
    int idx = u * 256 + tid;
    int rr = idx >> 4, seg = idx & 15;
    *(uint4*)(outb + (size_t)(rbase + rr) * 128 + seg * 8) = tl[rr * 17 + seg];
  }
  if (tid < 128) {
    float s = ssum[0][tid] + ssum[1][tid] + ssum[2][tid] + ssum[3][tid];
    float q = ssq[0][tid] + ssq[1][tid] + ssq[2][tid] + ssq[3][tid];
    int slot = blockIdx.x & (NSLOT - 1);
    atomicAdd(&statS[slot * 128 + tid], s);
    atomicAdd(&statQ[slot * 128 + tid], q);
  }
}

// ---------------- Pass A: Y aggregation + bn3 stats (LDS phase-reused) ----------------
// Phase 1: read t2, Y=relu(bn2(t2)) -> regs + swizzled ytile (32 KB)
// Phase 2: segmented aggregation of Y over sorted rows -> aggAcc atomics
// Phase 3: overwrite same LDS with swizzled W
// Phase 4: MFMA from register fragments + LDS W -> bn3 stats (no store)
__global__ __launch_bounds__(256) void k_caggstats(
    const unsigned short* __restrict__ t, const unsigned short* __restrict__ W,
    const float* __restrict__ bias, const float* __restrict__ bnS2,
    const float* __restrict__ bnSh2, const unsigned short* __restrict__ rowS,
    float* __restrict__ aggAcc, float* __restrict__ statS, float* __restrict__ statQ) {
  __shared__ __align__(16) unsigned short yb[128 * 128];  // ytile, then W (swizzled)
  __shared__ float ssum[4][128], ssq[4][128];
  int tid = threadIdx.x;
  int w = tid >> 6, lane = tid & 63, m = lane & 15, kq = lane >> 4;
  int rbase = blockIdx.x * 128;
  int r0l = w * 32 + m, r1l = r0l + 16;
  U8 ya0[4], ya1[4];
#pragma unroll
  for (int ks = 0; ks < 4; ++ks) {
    int k0 = ks * 32 + kq * 8;
    int blk = ks * 4 + kq;
    ya0[ks].u4 = *(const uint4*)(t + (size_t)(rbase + r0l) * 128 + k0);
    ya1[ks].u4 = *(const uint4*)(t + (size_t)(rbase + r1l) * 128 + k0);
    const float4* sp = (const float4*)(bnS2 + k0);
    const float4* hp = (const float4*)(bnSh2 + k0);
    float4 sA = sp[0], sB = sp[1], hA = hp[0], hB = hp[1];
    float sv[8] = {sA.x, sA.y, sA.z, sA.w, sB.x, sB.y, sB.z, sB.w};
    float hv[8] = {hA.x, hA.y, hA.z, hA.w, hB.x, hB.y, hB.z, hB.w};
#pragma unroll
    for (int j = 0; j < 8; ++j) {
      ya0[ks].us[j] = f2bf(fmaxf(bf2f(ya0[ks].us[j]) * sv[j] + hv[j], 0.f));
      ya1[ks].us[j] = f2bf(fmaxf(bf2f(ya1[ks].us[j]) * sv[j] + hv[j], 0.f));
    }
    *(uint4*)(yb + r0l * 128 + ((blk ^ m) << 3)) = ya0[ks].u4;
    *(uint4*)(yb + r1l * 128 + ((blk ^ m) << 3)) = ya1[ks].u4;
  }
  __syncthreads();
  // Phase 2: segmented column sums of Y over sorted rows
  {
    int ch = tid & 127, half = tid >> 7;
    int rlo = half * 64, rhi = rlo + 64;
    int cur = rowS[rbase + rlo];
    float run = 0.f;
    for (int r = rlo; r < rhi; ++r) {
      int nid = rowS[rbase + r];
      if (nid != cur) {
        atomicAdd(&aggAcc[(size_t)cur * 128 + ch], run);
        run = 0.f;
        cur = nid;
      }
      run += bf2f(yb[r * 128 + (((ch >> 3) ^ (r & 15)) << 3) + (ch & 7)]);
    }
    atomicAdd(&aggAcc[(size_t)cur * 128 + ch], run);
  }
  __syncthreads();
  // Phase 3: stage W (swizzled) over ytile
#pragma unroll
  for (int it = 0; it < 8; ++it) {
    int idx = it * 256 + tid;
    int n = idx >> 4, b = idx & 15;
    uint4 v = *(const uint4*)(W + (size_t)n * 128 + b * 8);
    *(uint4*)(yb + n * 128 + ((b ^ (n & 15)) << 3)) = v;
  }
  __syncthreads();
  // Phase 4: MFMA from retained register fragments
  f32x4 acc[2][8];
#pragma unroll
  for (int rt = 0; rt < 2; ++rt)
#pragma unroll
    for (int c = 0; c < 8; ++c) acc[rt][c] = (f32x4){0.f, 0.f, 0.f, 0.f};
#pragma unroll
  for (int ks = 0; ks < 4; ++ks) {
    int blk = ks * 4 + kq;
#pragma unroll
    for (int c = 0; c < 8; ++c) {
      U8 ub;
      ub.u4 = *(const uint4*)(yb + (c * 16 + m) * 128 + ((blk ^ m) << 3));
      acc[0][c] = __builtin_amdgcn_mfma_f32_16x16x32_bf16(ya0[ks].s8, ub.s8, acc[0][c], 0, 0, 0);
      acc[1][c] = __builtin_amdgcn_mfma_f32_16x16x32_bf16(ya1[ks].s8, ub.s8, acc[1][c], 0, 0, 0);
    }
  }
  // bn3 stats epilogue (t3 = acc + bias), all En rows valid (En % 128 == 0)
#pragma unroll
  for (int c = 0; c < 8; ++c) {
    int n = c * 16 + m;
    float bn_ = bias[n];
    float s = 0.f, q = 0.f;
#pragma unroll
    for (int rt = 0; rt < 2; ++rt)
#pragma unroll
      for (int j = 0; j < 4; ++j) {
        float v = acc[rt][c][j] + bn_;
        s += v;
        q = fmaf(v, v, q);
      }
    s += __shfl_xor(s, 16, 64); s += __shfl_xor(s, 32, 64);
    q += __shfl_xor(q, 16, 64); q += __shfl_xor(q, 32, 64);
    if (kq == 0) { ssum[w][n] = s; ssq[w][n] = q; }
  }
  __syncthreads();
  if (tid < 128) {
    float s = ssum[0][tid] + ssum[1][tid] + ssum[2][tid] + ssum[3][tid];
    float q = ssq[0][tid] + ssq[1][tid] + ssq[2][tid] + ssq[3][tid];
    int slot = blockIdx.x & (NSLOT - 1);
    atomicAdd(&statS[slot * 128 + tid], s);
    atomicAdd(&statQ[slot * 128 + tid], q);
  }
}

// ---------------- Pass B: coord-l1 GEMM + scale-dot only ----------------
__global__ __launch_bounds__(256) void k_cscale(
    const unsigned short* __restrict__ t, const unsigned short* __restrict__ W,
    const float* __restrict__ bias, const float* __restrict__ bnS2,
    const float* __restrict__ bnSh2, const float* __restrict__ bnS3,
    const float* __restrict__ bnSh3, const float* __restrict__ cw2,
    float* __restrict__ scaleE) {
  constexpr int WST = 136;
  __shared__ __align__(16) unsigned short smem[128 * WST];
  int tid = threadIdx.x;
  int w = tid >> 6, lane = tid & 63, m = lane & 15, kq = lane >> 4;
  int rbase = blockIdx.x * 128;
#pragma unroll
  for (int it = 0; it < 8; ++it) {
    int idx = it * 256 + tid;
    int n = idx >> 4, seg = idx & 15;
    uint4 v = *(const uint4*)(W + (size_t)n * 128 + seg * 8);
    *(uint4*)(smem + n * WST + seg * 8) = v;
  }
  __syncthreads();
  int r0l = w * 32 + m, r1l = r0l + 16;
  f32x4 acc[2][8];
#pragma unroll
  for (int rt = 0; rt < 2; ++rt)
#pragma unroll
    for (int c = 0; c < 8; ++c) acc[rt][c] = (f32x4){0.f, 0.f, 0.f, 0.f};
#pragma unroll
  for (int ks = 0; ks < 4; ++ks) {
    int k0 = ks * 32 + kq * 8;
    U8 ua0, ua1;
    ua0.u4 = *(const uint4*)(t + (size_t)(rbase + r0l) * 128 + k0);
    ua1.u4 = *(const uint4*)(t + (size_t)(rbase + r1l) * 128 + k0);
    const float4* sp = (const float4*)(bnS2 + k0);
    const float4* hp = (const float4*)(bnSh2 + k0);
    float4 sA = sp[0], sB = sp[1], hA = hp[0], hB = hp[1];
    float sv[8] = {sA.x, sA.y, sA.z, sA.w, sB.x, sB.y, sB.z, sB.w};
    float hv[8] = {hA.x, hA.y, hA.z, hA.w, hB.x, hB.y, hB.z, hB.w};
#pragma unroll
    for (int j = 0; j < 8; ++j) {
      ua0.us[j] = f2bf(fmaxf(bf2f(ua0.us[j]) * sv[j] + hv[j], 0.f));
      ua1.us[j] = f2bf(fmaxf(bf2f(ua1.us[j]) * sv[j] + hv[j], 0.f));
    }
#pragma unroll
    for (int c = 0; c < 8; ++c) {
      U8 ub;
      ub.u4 = *(const uint4*)(smem + (c * 16 + m) * WST + k0);
      acc[0][c] = __builtin_amdgcn_mfma_f32_16x16x32_bf16(ua0.s8, ub.s8, acc[0][c], 0, 0, 0);
      acc[1][c] = __builtin_amdgcn_mfma_f32_16x16x32_bf16(ua1.s8, ub.s8, acc[1][c], 0, 0, 0);
    }
  }
  float p[2][4] = {{0.f, 0.f, 0.f, 0.f}, {0.f, 0.f, 0.f, 0.f}};
#pragma unroll
  for (int c = 0; c < 8; ++c) {
    int n = c * 16 + m;
    float b1 = bias[n], s3 = bnS3[n], sh3 = bnSh3[n], w2 = cw2[n];
#pragma unroll
    for (int rt = 0; rt < 2; ++rt)
#pragma unroll
      for (int j = 0; j < 4; ++j) {
        float t3v = acc[rt][c][j] + b1;
        p[rt][j] += w2 * fmaxf(t3v * s3 + sh3, 0.f);
      }
  }
#pragma unroll
  for (int rt = 0; rt < 2; ++rt)
#pragma unroll
    for (int j = 0; j < 4; ++j) {
      float v = p[rt][j];
      v += __shfl_xor(v, 1, 64); v += __shfl_xor(v, 2, 64);
      v += __shfl_xor(v, 4, 64); v += __shfl_xor(v, 8, 64);
      if (m == 0) scaleE[rbase + w * 32 + rt * 16 + kq * 4 + j] = v;
    }
}

// aggAcc/deg -> nodeA[:,128:256] bf16
__global__ __launch_bounds__(256) void k_aggfin(const float* __restrict__ aggAcc,
                                                const int* __restrict__ cnt,
                                                unsigned short* __restrict__ nodeA) {
  int idx = blockIdx.x * 256 + threadIdx.x;
  if (idx >= Nn * 128) return;
  int n = idx >> 7, ch = idx & 127;
  float inv = 1.f / fmaxf((float)cnt[n], 1.f);
  nodeA[(size_t)n * 256 + 128 + ch] = f2bf(aggAcc[idx] * inv);
}

// coord_out: contiguous CSR ranges, coalesced
__global__ __launch_bounds__(256) void k_coord(const float* __restrict__ coord,
                                               const unsigned short* __restrict__ colS,
                                               const int* __restrict__ start,
                                               const int* __restrict__ cnt,
                                               const float* __restrict__ scaleE,
                                               float* __restrict__ cout) {
  int tid = threadIdx.x;
  int lane = tid & 63;
  int n = blockIdx.x * 4 + (tid >> 6);
  if (n >= Nn) return;
  int deg = cnt[n], off = start[n];
  float cx0 = coord[n * 3 + 0], cy0 = coord[n * 3 + 1], cz0 = coord[n * 3 + 2];
  float ax = 0.f, ay = 0.f, az = 0.f;
  for (int j = lane; j < deg; j += 64) {
    int e = off + j;
    int c = colS[e];
    float s = scaleE[e];
    float tx = (cx0 - coord[c * 3 + 0]) * s;
    float ty = (cy0 - coord[c * 3 + 1]) * s;
    float tz = (cz0 - coord[c * 3 + 2]) * s;
    ax += fminf(fmaxf(tx, -100.f), 100.f);
    ay += fminf(fmaxf(ty, -100.f), 100.f);
    az += fminf(fmaxf(tz, -100.f), 100.f);
  }
#pragma unroll
  for (int d = 32; d; d >>= 1) {
    ax += __shfl_xor(ax, d, 64);
    ay += __shfl_xor(ay, d, 64);
    az += __shfl_xor(az, d, 64);
  }
  if (lane == 0) {
    float inv = 1.f / fmaxf((float)deg, 1.f);
    cout[n * 3 + 0] = cx0 + ax * inv;
    cout[n * 3 + 1] = cy0 + ay * inv;
    cout[n * 3 + 2] = cz0 + az * inv;
  }
}

// ---------------- launcher ----------------

extern "C" void kernel_launch(void* const* d_in, const int* in_sizes, int n_in, void* d_out,
                              int out_size, void* d_ws, size_t ws_size, hipStream_t stream) {
  (void)in_sizes; (void)n_in; (void)out_size; (void)ws_size;
  const float* h = (const float*)d_in[0];
  const float* coord = (const float*)d_in[1];
  const int* eidx = (const int*)d_in[2];
  const int* row = eidx;
  const int* col = eidx + En;
  const float* e_w1 = (const float*)d_in[3];
  const float* e_b1 = (const float*)d_in[4];
  const float* e_g1 = (const float*)d_in[5];
  const float* e_be1 = (const float*)d_in[6];
  const float* e_w2 = (const float*)d_in[7];
  const float* e_b2 = (const float*)d_in[8];
  const float* e_g2 = (const float*)d_in[9];
  const float* e_be2 = (const float*)d_in[10];
  const float* n_w1 = (const float*)d_in[11];
  const float* n_b1 = (const float*)d_in[12];
  const float* n_g1 = (const float*)d_in[13];
  const float* n_be1 = (const float*)d_in[14];
  const float* n_w2 = (const float*)d_in[15];
  const float* n_b2 = (const float*)d_in[16];
  const float* c_w1 = (const float*)d_in[17];
  const float* c_b1 = (const float*)d_in[18];
  const float* c_g1 = (const float*)d_in[19];
  const float* c_be1 = (const float*)d_in[20];
  const float* c_w2 = (const float*)d_in[21];

  char* base = (char*)d_ws;
  size_t off = 0;
  auto alloc = [&](size_t bytes) -> void* {
    void* p = base + off;
    off = (off + bytes + 255) & ~(size_t)255;
    return p;
  };
  // Workspace budget: ~263.5 MB (round-3 proven footprint).
  unsigned short* t = (unsigned short*)alloc((size_t)En * 128 * 2);      // t2, later t4
  unsigned short* nodeA = (unsigned short*)alloc((size_t)Nn * 256 * 2);  // [h | agg] bf16
  unsigned short* hWr = (unsigned short*)alloc((size_t)Nn * 128 * 2);
  unsigned short* hWc = (unsigned short*)alloc((size_t)Nn * 128 * 2);
  float* aggAcc = (float*)hWr;  // alias: hWr+hWc contiguous 25.6MB, dead after k_egemm2
  float* scaleE = (float*)alloc((size_t)En * 4);
  float* radS = scaleE;  // alias: radS dead before scaleE is first written (k_cscale)
  unsigned short* rowS = (unsigned short*)alloc((size_t)En * 2);
  unsigned short* colS = (unsigned short*)alloc((size_t)En * 2);
  int* cnt = (int*)alloc((size_t)Nn * 4);
  int* startp = (int*)alloc((size_t)Nn * 4);
  int* cursor = (int*)alloc((size_t)Nn * 4);
  float* statS = (float*)alloc(4 * NSLOT * 128 * 4);
  float* statQ = (float*)alloc(4 * NSLOT * 128 * 4);
  float* bnS = (float*)alloc(4 * 128 * 4);
  float* bnSh = (float*)alloc(4 * 128 * 4);
  unsigned short* w1a = (unsigned short*)alloc(128 * 128 * 2);
  unsigned short* w1b = (unsigned short*)alloc(128 * 128 * 2);
  unsigned short* w2b = (unsigned short*)alloc(128 * 128 * 2);
  unsigned short* c1b = (unsigned short*)alloc(128 * 128 * 2);
  unsigned short* n1b = (unsigned short*)alloc(128 * 256 * 2);
  unsigned short* n2b = (unsigned short*)alloc(128 * 128 * 2);
  float* wlast = (float*)alloc(128 * 4);

  hipMemsetAsync(cnt, 0, (size_t)Nn * 4, stream);
  hipMemsetAsync(statS, 0, 4 * NSLOT * 128 * 4, stream);
  hipMemsetAsync(statQ, 0, 4 * NSLOT * 128 * 4, stream);

  // prep
  k_prep_h<<<(Nn * 128 + 255) / 256, 256, 0, stream>>>(h, nodeA);
  k_prep_w<<<(128 * 128 + 255) / 256, 256, 0, stream>>>(e_w1, w1a, 257, 0, 7, 128 * 128);
  k_prep_w<<<(128 * 128 + 255) / 256, 256, 0, stream>>>(e_w1, w1b, 257, 128, 7, 128 * 128);
  k_prep_w<<<(128 * 128 + 255) / 256, 256, 0, stream>>>(e_w2, w2b, 128, 0, 7, 128 * 128);
  k_prep_w<<<(128 * 128 + 255) / 256, 256, 0, stream>>>(c_w1, c1b, 128, 0, 7, 128 * 128);
  k_prep_w<<<(128 * 256 + 255) / 256, 256, 0, stream>>>(n_w1, n1b, 256, 0, 8, 128 * 256);
  k_prep_w<<<(128 * 128 + 255) / 256, 256, 0, stream>>>(n_w2, n2b, 128, 0, 7, 128 * 128);
  k_wlast<<<1, 128, 0, stream>>>(e_w1, wlast);

  // CSR sort
  k_count<<<En / 256, 256, 0, stream>>>(row, cnt);
  k_scan<<<1, 1024, 0, stream>>>(cnt, startp, cursor, Nn);
  k_fill<<<En / 256, 256, 0, stream>>>(row, col, cursor, rowS, colS);

  // hW partial GEMMs (bias e_b1 folded into hWr)
  const int gridN = (Nn + 127) / 128;
  k_gemmW<4, false, false, false, true><<<gridN, 256, 0, stream>>>(
      nodeA, 256, w1a, e_b1, nullptr, nullptr, hWr, nullptr, nullptr, nullptr, nullptr, Nn);
  k_gemmW<4, false, false, false, true><<<gridN, 256, 0, stream>>>(
      nodeA, 256, w1b, nullptr, nullptr, nullptr, hWc, nullptr, nullptr, nullptr, nullptr, Nn);

  // bn1 stats over virtual t1 + radS
  const int per_wave = (En + 5119) / 5120;  // 1280 blocks * 4 waves
  k_stats1<<<1280, 256, 0, stream>>>(hWr, hWc, coord, rowS, colS, wlast, radS,
                                     statS + 0 * NSLOT * 128, statQ + 0 * NSLOT * 128, per_wave);
  k_fin<<<1, 128, 0, stream>>>(statS + 0 * NSLOT * 128, statQ + 0 * NSLOT * 128, e_g1, e_be1,
                               1.f / En, bnS + 0, bnSh + 0);

  // edge layer 2: t2 + bn2 stats (slot 1)
  k_egemm2<<<En / 128, 256, 0, stream>>>(hWr, hWc, radS, rowS, colS, w2b, e_b2, wlast, bnS + 0,
                                         bnSh + 0, t, statS + 1 * NSLOT * 128,
                                         statQ + 1 * NSLOT * 128);
  k_fin<<<1, 128, 0, stream>>>(statS + 1 * NSLOT * 128, statQ + 1 * NSLOT * 128, e_g2, e_be2,
                               1.f / En, bnS + 128, bnSh + 128);

  // hWr/hWc now dead -> init aggAcc (aliases them)
  hipMemsetAsync(aggAcc, 0, (size_t)Nn * 128 * 4, stream);

  // Pass A: aggregation of Y + bn3 stats (slot 2), single read of t
  k_caggstats<<<En / 128, 256, 0, stream>>>(t, c1b, c_b1, bnS + 128, bnSh + 128, rowS, aggAcc,
                                            statS + 2 * NSLOT * 128, statQ + 2 * NSLOT * 128);
  k_fin<<<1, 128, 0, stream>>>(statS + 2 * NSLOT * 128, statQ + 2 * NSLOT * 128, c_g1, c_be1,
                               1.f / En, bnS + 256, bnSh + 256);

  // Pass B: coord-l1 GEMM + scale dot -> scaleE (radS dead; scaleE written now)
  k_cscale<<<En / 128, 256, 0, stream>>>(t, c1b, c_b1, bnS + 128, bnSh + 128, bnS + 256,
                                         bnSh + 256, c_w2, scaleE);
  k_aggfin<<<(Nn * 128 + 255) / 256, 256, 0, stream>>>(aggAcc, cnt, nodeA);

  float* hout = (float*)d_out;
  float* cout = hout + (size_t)Nn * 128;
  k_coord<<<(Nn + 3) / 4, 256, 0, stream>>>(coord, colS, startp, cnt, scaleE, cout);

  // node MLP: l1 (stats slot 3) -> t4 in t; l2 fp32 residual out
  k_gemmW<8, false, true, false, true><<<gridN, 256, 0, stream>>>(
      nodeA, 256, n1b, n_b1, nullptr, nullptr, t, statS + 3 * NSLOT * 128,
      statQ + 3 * NSLOT * 128, nullptr, nullptr, Nn);
  k_fin<<<1, 128, 0, stream>>>(statS + 3 * NSLOT * 128, statQ + 3 * NSLOT * 128, n_g1, n_be1,
                               1.f / Nn, bnS + 384, bnSh + 384);
  k_gemmW<4, true, false, true, true><<<gridN, 256, 0, stream>>>(
      t, 128, n2b, n_b2, bnS + 384, bnSh + 384, nullptr, nullptr, nullptr, h, hout, Nn);
}

// Round 7
// 887.855 us; speedup vs baseline: 1.0965x; 1.0965x over previous
//
#include <hip/hip_runtime.h>

#define Nn 50000
#define En 800000
#define NSLOT 64

typedef __attribute__((ext_vector_type(8))) short short8;
typedef __attribute__((ext_vector_type(4))) float f32x4;

union U8 { uint4 u4; unsigned short us[8]; short8 s8; };

static __device__ __forceinline__ float bf2f(unsigned int lo16) {
  return __uint_as_float(lo16 << 16);
}
static __device__ __forceinline__ unsigned short f2bf(float f) {
  unsigned int x = __float_as_uint(f);
  return (unsigned short)((x + 0x7FFFu + ((x >> 16) & 1u)) >> 16);
}

// ---------------- prep kernels ----------------

__global__ __launch_bounds__(256) void k_prep_h(const float* __restrict__ h,
                                                unsigned short* __restrict__ nodeA) {
  int idx = blockIdx.x * 256 + threadIdx.x;
  if (idx >= Nn * 128) return;
  int n = idx >> 7, k = idx & 127;
  nodeA[(size_t)n * 256 + k] = f2bf(h[idx]);
}

// weight fp32 [128][Ksrc] cols [koff, koff+2^kshift) -> bf16 [128][2^kshift]
__global__ __launch_bounds__(256) void k_prep_w(const float* __restrict__ src,
                                                unsigned short* __restrict__ dst, int Ksrc,
                                                int koff, int kshift, int total) {
  int idx = blockIdx.x * 256 + threadIdx.x;
  if (idx >= total) return;
  int n = idx >> kshift;
  int k = idx & ((1 << kshift) - 1);
  dst[idx] = f2bf(src[n * Ksrc + koff + k]);
}

__global__ void k_wlast(const float* __restrict__ e_w1, float* __restrict__ wlast) {
  int t = threadIdx.x;
  if (t < 128) wlast[t] = e_w1[t * 257 + 256];
}

// ---------------- CSR build (edges sorted by row; node ids fit u16) ----------------

__global__ __launch_bounds__(256) void k_count(const int* __restrict__ row, int* __restrict__ cnt) {
  int e = blockIdx.x * 256 + threadIdx.x;
  atomicAdd(&cnt[row[e]], 1);
}

__global__ __launch_bounds__(256) void k_fill(const int* __restrict__ row,
                                              const int* __restrict__ col,
                                              int* __restrict__ cursor,
                                              unsigned short* __restrict__ rowS,
                                              unsigned short* __restrict__ colS) {
  int e = blockIdx.x * 256 + threadIdx.x;
  int r = row[e];
  int pos = atomicAdd(&cursor[r], 1);
  rowS[pos] = (unsigned short)r;
  colS[pos] = (unsigned short)col[e];
}

__global__ __launch_bounds__(1024) void k_scan(const int* __restrict__ cnt, int* __restrict__ start,
                                               int* __restrict__ cursor, int n) {
  __shared__ int wsum[16];
  __shared__ int carry;
  int tid = threadIdx.x, lane = tid & 63, wid = tid >> 6;
  if (tid == 0) carry = 0;
  __syncthreads();
  for (int base = 0; base < n; base += 1024) {
    int i = base + tid;
    int v = (i < n) ? cnt[i] : 0;
    int x = v;
#pragma unroll
    for (int d = 1; d < 64; d <<= 1) {
      int y = __shfl_up(x, d, 64);
      if (lane >= d) x += y;
    }
    if (lane == 63) wsum[wid] = x;
    __syncthreads();
    if (wid == 0) {
      int s = (lane < 16) ? wsum[lane] : 0;
#pragma unroll
      for (int d = 1; d < 16; d <<= 1) {
        int y = __shfl_up(s, d, 64);
        if (lane >= d) s += y;
      }
      if (lane < 16) wsum[lane] = s;
    }
    __syncthreads();
    int c0 = carry;
    int waveoff = (wid > 0) ? wsum[wid - 1] : 0;
    int incl = c0 + waveoff + x;
    if (i < n) {
      start[i] = incl - v;
      cursor[i] = incl - v;
    }
    __syncthreads();
    if (tid == 1023) carry = incl;
    __syncthreads();
  }
}

// ---------------- BN finalize ----------------

__global__ void k_fin(const float* __restrict__ statS, const float* __restrict__ statQ,
                      const float* __restrict__ g, const float* __restrict__ be, float invR,
                      float* __restrict__ bnS, float* __restrict__ bnSh) {
  int c = threadIdx.x;
  if (c >= 128) return;
  float s = 0.f, q = 0.f;
  for (int k = 0; k < NSLOT; ++k) {
    s += statS[k * 128 + c];
    q += statQ[k * 128 + c];
  }
  float mean = s * invR;
  float var = fmaxf(q * invR - mean * mean, 0.f);
  float rs = rsqrtf(var + 1e-5f);
  float sc = g[c] * rs;
  bnS[c] = sc;
  bnSh[c] = be[c] - mean * sc;
}

// ---------------- generic MFMA GEMM with W in LDS ----------------
template <int KSTEPS, bool BN_A, bool STATS, bool FP32OUT, bool STORE>
__global__ __launch_bounds__(256) void k_gemmW(
    const unsigned short* __restrict__ A, int Astride,
    const unsigned short* __restrict__ W, const float* __restrict__ bias,
    const float* __restrict__ bnS, const float* __restrict__ bnSh,
    unsigned short* __restrict__ outb, float* __restrict__ statS, float* __restrict__ statQ,
    const float* __restrict__ hres, float* __restrict__ outf, int R) {
  constexpr int K = KSTEPS * 32;
  constexpr int WST = K + 8;
  constexpr int SEGS = K / 8;
  __shared__ __align__(16) unsigned short smem[128 * WST];
  __shared__ float ssum[4][128], ssq[4][128];
  int tid = threadIdx.x;
  int w = tid >> 6, lane = tid & 63, m = lane & 15, kq = lane >> 4;
  int rbase = blockIdx.x * 128;
#pragma unroll
  for (int it = 0; it < SEGS / 2; ++it) {
    int idx = it * 256 + tid;
    int n = idx / SEGS, seg = idx % SEGS;
    uint4 v = *(const uint4*)(W + (size_t)n * K + seg * 8);
    *(uint4*)(smem + n * WST + seg * 8) = v;
  }
  __syncthreads();
  int row0 = rbase + w * 32 + m;
  int rc0 = min(row0, R - 1);
  int rc1 = min(row0 + 16, R - 1);
  f32x4 acc[2][8];
#pragma unroll
  for (int rt = 0; rt < 2; ++rt)
#pragma unroll
    for (int c = 0; c < 8; ++c) acc[rt][c] = (f32x4){0.f, 0.f, 0.f, 0.f};
#pragma unroll
  for (int ks = 0; ks < KSTEPS; ++ks) {
    int k0 = ks * 32 + kq * 8;
    U8 ua0, ua1;
    ua0.u4 = *(const uint4*)(A + (size_t)rc0 * Astride + k0);
    ua1.u4 = *(const uint4*)(A + (size_t)rc1 * Astride + k0);
    if (BN_A) {
      const float4* sp = (const float4*)(bnS + k0);
      const float4* hp = (const float4*)(bnSh + k0);
      float4 s0 = sp[0], s1 = sp[1], h0 = hp[0], h1 = hp[1];
      float sv[8] = {s0.x, s0.y, s0.z, s0.w, s1.x, s1.y, s1.z, s1.w};
      float hv[8] = {h0.x, h0.y, h0.z, h0.w, h1.x, h1.y, h1.z, h1.w};
#pragma unroll
      for (int j = 0; j < 8; ++j) {
        ua0.us[j] = f2bf(fmaxf(bf2f(ua0.us[j]) * sv[j] + hv[j], 0.f));
        ua1.us[j] = f2bf(fmaxf(bf2f(ua1.us[j]) * sv[j] + hv[j], 0.f));
      }
    }
#pragma unroll
    for (int c = 0; c < 8; ++c) {
      U8 ub;
      ub.u4 = *(const uint4*)(smem + (c * 16 + m) * WST + k0);
      acc[0][c] = __builtin_amdgcn_mfma_f32_16x16x32_bf16(ua0.s8, ub.s8, acc[0][c], 0, 0, 0);
      acc[1][c] = __builtin_amdgcn_mfma_f32_16x16x32_bf16(ua1.s8, ub.s8, acc[1][c], 0, 0, 0);
    }
  }
  if constexpr (FP32OUT) {
#pragma unroll
    for (int rt = 0; rt < 2; ++rt)
#pragma unroll
      for (int c = 0; c < 8; ++c) {
        int n = c * 16 + m;
        float bn_ = bias[n];
#pragma unroll
        for (int j = 0; j < 4; ++j) {
          int rr = rbase + w * 32 + rt * 16 + kq * 4 + j;
          if (rr < R) {
            size_t o = (size_t)rr * 128 + n;
            outf[o] = acc[rt][c][j] + bn_ + hres[o];
          }
        }
      }
  } else {
    if constexpr (STORE) __syncthreads();
    unsigned short* tile = smem;  // reuse as [128][136]
#pragma unroll
    for (int c = 0; c < 8; ++c) {
      int n = c * 16 + m;
      float bn_ = bias ? bias[n] : 0.f;
      float s = 0.f, q = 0.f;
#pragma unroll
      for (int rt = 0; rt < 2; ++rt)
#pragma unroll
        for (int j = 0; j < 4; ++j) {
          int lr = w * 32 + rt * 16 + kq * 4 + j;
          float v = acc[rt][c][j] + bn_;
          if (STORE) tile[lr * 136 + n] = f2bf(v);
          if (STATS) {
            float sv = (rbase + lr < R) ? v : 0.f;
            s += sv;
            q = fmaf(sv, sv, q);
          }
        }
      if (STATS) {
        s += __shfl_xor(s, 16, 64); s += __shfl_xor(s, 32, 64);
        q += __shfl_xor(q, 16, 64); q += __shfl_xor(q, 32, 64);
        if (kq == 0) { ssum[w][n] = s; ssq[w][n] = q; }
      }
    }
    if constexpr (STORE) {
      __syncthreads();
      const uint4* tl = (const uint4*)tile;
#pragma unroll
      for (int u = 0; u < 8; ++u) {
        int idx = u * 256 + tid;
        int rr = idx >> 4, seg = idx & 15;
        if (rbase + rr < R)
          *(uint4*)(outb + (size_t)(rbase + rr) * 128 + seg * 8) = tl[rr * 17 + seg];
      }
    }
    if (STATS) {
      __syncthreads();
      if (tid < 128) {
        float s = ssum[0][tid] + ssum[1][tid] + ssum[2][tid] + ssum[3][tid];
        float q = ssq[0][tid] + ssq[1][tid] + ssq[2][tid] + ssq[3][tid];
        int slot = blockIdx.x & (NSLOT - 1);
        atomicAdd(&statS[slot * 128 + tid], s);
        atomicAdd(&statQ[slot * 128 + tid], q);
      }
    }
  }
}

// ---------------- bn1 stats over virtual t1 (no materialization) + radS ----------------
__global__ __launch_bounds__(256) void k_stats1(
    const unsigned short* __restrict__ hWr, const unsigned short* __restrict__ hWc,
    const float* __restrict__ coord, const unsigned short* __restrict__ rowS,
    const unsigned short* __restrict__ colS, const float* __restrict__ wlast,
    float* __restrict__ radS, float* __restrict__ statS, float* __restrict__ statQ,
    int per_wave) {
  int tid = threadIdx.x, lane = tid & 63;
  int wid = blockIdx.x * 4 + (tid >> 6);
  int e0 = wid * per_wave;
  int e1 = min(e0 + per_wave, En);
  int c2 = lane * 2;
  float wl0 = wlast[c2], wl1 = wlast[c2 + 1];
  float s0 = 0.f, s1 = 0.f, q0 = 0.f, q1 = 0.f;
  for (int e = e0; e < e1; ++e) {
    int r = rowS[e], c = colS[e];
    float dx = coord[r * 3 + 0] - coord[c * 3 + 0];
    float dy = coord[r * 3 + 1] - coord[c * 3 + 1];
    float dz = coord[r * 3 + 2] - coord[c * 3 + 2];
    float rad = dx * dx + dy * dy + dz * dz;
    if (lane == 0) radS[e] = rad;
    unsigned int ua = *(const unsigned int*)(hWr + (size_t)r * 128 + c2);
    unsigned int ub = *(const unsigned int*)(hWc + (size_t)c * 128 + c2);
    float v0 = bf2f(ua & 0xFFFFu) + bf2f(ub & 0xFFFFu) + rad * wl0;
    float v1 = bf2f(ua >> 16) + bf2f(ub >> 16) + rad * wl1;
    s0 += v0; q0 = fmaf(v0, v0, q0);
    s1 += v1; q1 = fmaf(v1, v1, q1);
  }
  int slot = wid & (NSLOT - 1);
  atomicAdd(&statS[slot * 128 + c2], s0);
  atomicAdd(&statS[slot * 128 + c2 + 1], s1);
  atomicAdd(&statQ[slot * 128 + c2], q0);
  atomicAdd(&statQ[slot * 128 + c2 + 1], q1);
}

// ---------------- edge layer 2 GEMM, A recomputed from hWr/hWc/radS ----------------
__global__ __launch_bounds__(256) void k_egemm2(
    const unsigned short* __restrict__ hWr, const unsigned short* __restrict__ hWc,
    const float* __restrict__ radS, const unsigned short* __restrict__ rowS,
    const unsigned short* __restrict__ colS, const unsigned short* __restrict__ W,
    const float* __restrict__ bias, const float* __restrict__ wlast,
    const float* __restrict__ bnS1, const float* __restrict__ bnSh1,
    unsigned short* __restrict__ outb, float* __restrict__ statS, float* __restrict__ statQ) {
  constexpr int WST = 136;
  __shared__ __align__(16) unsigned short smem[128 * WST];
  __shared__ float ssum[4][128], ssq[4][128];
  int tid = threadIdx.x;
  int w = tid >> 6, lane = tid & 63, m = lane & 15, kq = lane >> 4;
  int rbase = blockIdx.x * 128;
#pragma unroll
  for (int it = 0; it < 8; ++it) {
    int idx = it * 256 + tid;
    int n = idx >> 4, seg = idx & 15;
    uint4 v = *(const uint4*)(W + (size_t)n * 128 + seg * 8);
    *(uint4*)(smem + n * WST + seg * 8) = v;
  }
  int rc0 = rbase + w * 32 + m, rc1 = rc0 + 16;
  int r0 = rowS[rc0], c0 = colS[rc0];
  int r1 = rowS[rc1], c1 = colS[rc1];
  float rad0 = radS[rc0], rad1 = radS[rc1];
  __syncthreads();
  f32x4 acc[2][8];
#pragma unroll
  for (int rt = 0; rt < 2; ++rt)
#pragma unroll
    for (int c = 0; c < 8; ++c) acc[rt][c] = (f32x4){0.f, 0.f, 0.f, 0.f};
#pragma unroll
  for (int ks = 0; ks < 4; ++ks) {
    int k0 = ks * 32 + kq * 8;
    U8 a0r, a0c, a1r, a1c;
    a0r.u4 = *(const uint4*)(hWr + (size_t)r0 * 128 + k0);
    a0c.u4 = *(const uint4*)(hWc + (size_t)c0 * 128 + k0);
    a1r.u4 = *(const uint4*)(hWr + (size_t)r1 * 128 + k0);
    a1c.u4 = *(const uint4*)(hWc + (size_t)c1 * 128 + k0);
    const float4* wp = (const float4*)(wlast + k0);
    const float4* sp = (const float4*)(bnS1 + k0);
    const float4* hp = (const float4*)(bnSh1 + k0);
    float4 w0 = wp[0], w1 = wp[1], sA = sp[0], sB = sp[1], hA = hp[0], hB = hp[1];
    float wv[8] = {w0.x, w0.y, w0.z, w0.w, w1.x, w1.y, w1.z, w1.w};
    float sv[8] = {sA.x, sA.y, sA.z, sA.w, sB.x, sB.y, sB.z, sB.w};
    float hv[8] = {hA.x, hA.y, hA.z, hA.w, hB.x, hB.y, hB.z, hB.w};
    U8 ua0, ua1;
#pragma unroll
    for (int j = 0; j < 8; ++j) {
      float v0 = bf2f(a0r.us[j]) + bf2f(a0c.us[j]) + rad0 * wv[j];
      float v1 = bf2f(a1r.us[j]) + bf2f(a1c.us[j]) + rad1 * wv[j];
      ua0.us[j] = f2bf(fmaxf(v0 * sv[j] + hv[j], 0.f));
      ua1.us[j] = f2bf(fmaxf(v1 * sv[j] + hv[j], 0.f));
    }
#pragma unroll
    for (int c = 0; c < 8; ++c) {
      U8 ub;
      ub.u4 = *(const uint4*)(smem + (c * 16 + m) * WST + k0);
      acc[0][c] = __builtin_amdgcn_mfma_f32_16x16x32_bf16(ua0.s8, ub.s8, acc[0][c], 0, 0, 0);
      acc[1][c] = __builtin_amdgcn_mfma_f32_16x16x32_bf16(ua1.s8, ub.s8, acc[1][c], 0, 0, 0);
    }
  }
  __syncthreads();
  unsigned short* tile = smem;
#pragma unroll
  for (int c = 0; c < 8; ++c) {
    int n = c * 16 + m;
    float bn_ = bias[n];
    float s = 0.f, q = 0.f;
#pragma unroll
    for (int rt = 0; rt < 2; ++rt)
#pragma unroll
      for (int j = 0; j < 4; ++j) {
        int lr = w * 32 + rt * 16 + kq * 4 + j;
        float v = acc[rt][c][j] + bn_;
        tile[lr * 136 + n] = f2bf(v);
        s += v;
        q = fmaf(v, v, q);
      }
    s += __shfl_xor(s, 16, 64); s += __shfl_xor(s, 32, 64);
    q += __shfl_xor(q, 16, 64); q += __shfl_xor(q, 32, 64);
    if (kq == 0) { ssum[w][n] = s; ssq[w][n] = q; }
  }
  __syncthreads();
  const uint4* tl = (const uint4*)tile;
#pragma unroll
  for (int u = 0; u < 8; ++u) {
    int idx = u * 256 + tid;
    int rr = idx >> 4, seg = idx & 15;
    *(uint4*)(outb + (size_t)(rbase + rr) * 128 + seg * 8) = tl[rr * 17 + seg];
  }
  if (tid < 128) {
    float s = ssum[0][tid] + ssum[1][tid] + ssum[2][tid] + ssum[3][tid];
    float q = ssq[0][tid] + ssq[1][tid] + ssq[2][tid] + ssq[3][tid];
    int slot = blockIdx.x & (NSLOT - 1);
    atomicAdd(&statS[slot * 128 + tid], s);
    atomicAdd(&statQ[slot * 128 + tid], q);
  }
}

// ---------------- Pass A: Y aggregation + bn3 stats ----------------
// Phase 1: read t2, Y=relu(bn2(t2)) -> regs + swizzled ytile; preload srow to LDS
// Phase 2: segmented column sums over sorted rows — LDS-srow branches, 4 independent
//          8-row chains per thread (ILP), flush at chunk boundaries
// Phase 3: overwrite LDS with swizzled W;  Phase 4: MFMA -> bn3 stats
__global__ __launch_bounds__(256) void k_caggstats(
    const unsigned short* __restrict__ t, const unsigned short* __restrict__ W,
    const float* __restrict__ bias, const float* __restrict__ bnS2,
    const float* __restrict__ bnSh2, const unsigned short* __restrict__ rowS,
    float* __restrict__ aggAcc, float* __restrict__ statS, float* __restrict__ statQ) {
  __shared__ __align__(16) unsigned short yb[128 * 128];  // ytile, then W (swizzled)
  __shared__ float ssum[4][128], ssq[4][128];
  __shared__ int srow[128];
  int tid = threadIdx.x;
  int w = tid >> 6, lane = tid & 63, m = lane & 15, kq = lane >> 4;
  int rbase = blockIdx.x * 128;
  if (tid < 64) {
    unsigned int rr = *(const unsigned int*)(rowS + rbase + tid * 2);
    srow[tid * 2] = (int)(rr & 0xFFFFu);
    srow[tid * 2 + 1] = (int)(rr >> 16);
  }
  int r0l = w * 32 + m, r1l = r0l + 16;
  U8 ya0[4], ya1[4];
#pragma unroll
  for (int ks = 0; ks < 4; ++ks) {
    int k0 = ks * 32 + kq * 8;
    int blk = ks * 4 + kq;
    ya0[ks].u4 = *(const uint4*)(t + (size_t)(rbase + r0l) * 128 + k0);
    ya1[ks].u4 = *(const uint4*)(t + (size_t)(rbase + r1l) * 128 + k0);
    const float4* sp = (const float4*)(bnS2 + k0);
    const float4* hp = (const float4*)(bnSh2 + k0);
    float4 sA = sp[0], sB = sp[1], hA = hp[0], hB = hp[1];
    float sv[8] = {sA.x, sA.y, sA.z, sA.w, sB.x, sB.y, sB.z, sB.w};
    float hv[8] = {hA.x, hA.y, hA.z, hA.w, hB.x, hB.y, hB.z, hB.w};
#pragma unroll
    for (int j = 0; j < 8; ++j) {
      ya0[ks].us[j] = f2bf(fmaxf(bf2f(ya0[ks].us[j]) * sv[j] + hv[j], 0.f));
      ya1[ks].us[j] = f2bf(fmaxf(bf2f(ya1[ks].us[j]) * sv[j] + hv[j], 0.f));
    }
    *(uint4*)(yb + r0l * 128 + ((blk ^ m) << 3)) = ya0[ks].u4;
    *(uint4*)(yb + r1l * 128 + ((blk ^ m) << 3)) = ya1[ks].u4;
  }
  __syncthreads();
  // Phase 2: wave qtr handles rows [qtr*32, +32) as 4 chunks of 8; lane -> channel pair
  {
    int c2 = (tid & 63) * 2;
    int qtr = tid >> 6;
#pragma unroll
    for (int c4 = 0; c4 < 4; ++c4) {
      int rlo = qtr * 32 + c4 * 8;
      int cur = srow[rlo];
      float run0 = 0.f, run1 = 0.f;
#pragma unroll
      for (int r = rlo; r < rlo + 8; ++r) {
        int nid = srow[r];
        if (nid != cur) {
          atomicAdd(&aggAcc[(size_t)cur * 128 + c2], run0);
          atomicAdd(&aggAcc[(size_t)cur * 128 + c2 + 1], run1);
          run0 = 0.f; run1 = 0.f; cur = nid;
        }
        unsigned int u =
            *(const unsigned int*)(yb + r * 128 + (((c2 >> 3) ^ (r & 15)) << 3) + (c2 & 7));
        run0 += bf2f(u & 0xFFFFu);
        run1 += bf2f(u >> 16);
      }
      atomicAdd(&aggAcc[(size_t)cur * 128 + c2], run0);
      atomicAdd(&aggAcc[(size_t)cur * 128 + c2 + 1], run1);
    }
  }
  __syncthreads();
  // Phase 3: stage W (swizzled) over ytile
#pragma unroll
  for (int it = 0; it < 8; ++it) {
    int idx = it * 256 + tid;
    int n = idx >> 4, b = idx & 15;
    uint4 v = *(const uint4*)(W + (size_t)n * 128 + b * 8);
    *(uint4*)(yb + n * 128 + ((b ^ (n & 15)) << 3)) = v;
  }
  __syncthreads();
  // Phase 4: MFMA from retained register fragments
  f32x4 acc[2][8];
#pragma unroll
  for (int rt = 0; rt < 2; ++rt)
#pragma unroll
    for (int c = 0; c < 8; ++c) acc[rt][c] = (f32x4){0.f, 0.f, 0.f, 0.f};
#pragma unroll
  for (int ks = 0; ks < 4; ++ks) {
    int blk = ks * 4 + kq;
#pragma unroll
    for (int c = 0; c < 8; ++c) {
      U8 ub;
      ub.u4 = *(const uint4*)(yb + (c * 16 + m) * 128 + ((blk ^ m) << 3));
      acc[0][c] = __builtin_amdgcn_mfma_f32_16x16x32_bf16(ya0[ks].s8, ub.s8, acc[0][c], 0, 0, 0);
      acc[1][c] = __builtin_amdgcn_mfma_f32_16x16x32_bf16(ya1[ks].s8, ub.s8, acc[1][c], 0, 0, 0);
    }
  }
  // bn3 stats epilogue (t3 = acc + bias), all En rows valid (En % 128 == 0)
#pragma unroll
  for (int c = 0; c < 8; ++c) {
    int n = c * 16 + m;
    float bn_ = bias[n];
    float s = 0.f, q = 0.f;
#pragma unroll
    for (int rt = 0; rt < 2; ++rt)
#pragma unroll
      for (int j = 0; j < 4; ++j) {
        float v = acc[rt][c][j] + bn_;
        s += v;
        q = fmaf(v, v, q);
      }
    s += __shfl_xor(s, 16, 64); s += __shfl_xor(s, 32, 64);
    q += __shfl_xor(q, 16, 64); q += __shfl_xor(q, 32, 64);
    if (kq == 0) { ssum[w][n] = s; ssq[w][n] = q; }
  }
  __syncthreads();
  if (tid < 128) {
    float s = ssum[0][tid] + ssum[1][tid] + ssum[2][tid] + ssum[3][tid];
    float q = ssq[0][tid] + ssq[1][tid] + ssq[2][tid] + ssq[3][tid];
    int slot = blockIdx.x & (NSLOT - 1);
    atomicAdd(&statS[slot * 128 + tid], s);
    atomicAdd(&statQ[slot * 128 + tid], q);
  }
}

// ---------------- Pass B: coord-l1 GEMM + scale-dot only ----------------
__global__ __launch_bounds__(256) void k_cscale(
    const unsigned short* __restrict__ t, const unsigned short* __restrict__ W,
    const float* __restrict__ bias, const float* __restrict__ bnS2,
    const float* __restrict__ bnSh2, const float* __restrict__ bnS3,
    const float* __restrict__ bnSh3, const float* __restrict__ cw2,
    float* __restrict__ scaleE) {
  constexpr int WST = 136;
  __shared__ __align__(16) unsigned short smem[128 * WST];
  int tid = threadIdx.x;
  int w = tid >> 6, lane = tid & 63, m = lane & 15, kq = lane >> 4;
  int rbase = blockIdx.x * 128;
#pragma unroll
  for (int it = 0; it < 8; ++it) {
    int idx = it * 256 + tid;
    int n = idx >> 4, seg = idx & 15;
    uint4 v = *(const uint4*)(W + (size_t)n * 128 + seg * 8);
    *(uint4*)(smem + n * WST + seg * 8) = v;
  }
  __syncthreads();
  int r0l = w * 32 + m, r1l = r0l + 16;
  f32x4 acc[2][8];
#pragma unroll
  for (int rt = 0; rt < 2; ++rt)
#pragma unroll
    for (int c = 0; c < 8; ++c) acc[rt][c] = (f32x4){0.f, 0.f, 0.f, 0.f};
#pragma unroll
  for (int ks = 0; ks < 4; ++ks) {
    int k0 = ks * 32 + kq * 8;
    U8 ua0, ua1;
    ua0.u4 = *(const uint4*)(t + (size_t)(rbase + r0l) * 128 + k0);
    ua1.u4 = *(const uint4*)(t + (size_t)(rbase + r1l) * 128 + k0);
    const float4* sp = (const float4*)(bnS2 + k0);
    const float4* hp = (const float4*)(bnSh2 + k0);
    float4 sA = sp[0], sB = sp[1], hA = hp[0], hB = hp[1];
    float sv[8] = {sA.x, sA.y, sA.z, sA.w, sB.x, sB.y, sB.z, sB.w};
    float hv[8] = {hA.x, hA.y, hA.z, hA.w, hB.x, hB.y, hB.z, hB.w};
#pragma unroll
    for (int j = 0; j < 8; ++j) {
      ua0.us[j] = f2bf(fmaxf(bf2f(ua0.us[j]) * sv[j] + hv[j], 0.f));
      ua1.us[j] = f2bf(fmaxf(bf2f(ua1.us[j]) * sv[j] + hv[j], 0.f));
    }
#pragma unroll
    for (int c = 0; c < 8; ++c) {
      U8 ub;
      ub.u4 = *(const uint4*)(smem + (c * 16 + m) * WST + k0);
      acc[0][c] = __builtin_amdgcn_mfma_f32_16x16x32_bf16(ua0.s8, ub.s8, acc[0][c], 0, 0, 0);
      acc[1][c] = __builtin_amdgcn_mfma_f32_16x16x32_bf16(ua1.s8, ub.s8, acc[1][c], 0, 0, 0);
    }
  }
  float p[2][4] = {{0.f, 0.f, 0.f, 0.f}, {0.f, 0.f, 0.f, 0.f}};
#pragma unroll
  for (int c = 0; c < 8; ++c) {
    int n = c * 16 + m;
    float b1 = bias[n], s3 = bnS3[n], sh3 = bnSh3[n], w2 = cw2[n];
#pragma unroll
    for (int rt = 0; rt < 2; ++rt)
#pragma unroll
      for (int j = 0; j < 4; ++j) {
        float t3v = acc[rt][c][j] + b1;
        p[rt][j] += w2 * fmaxf(t3v * s3 + sh3, 0.f);
      }
  }
#pragma unroll
  for (int rt = 0; rt < 2; ++rt)
#pragma unroll
    for (int j = 0; j < 4; ++j) {
      float v = p[rt][j];
      v += __shfl_xor(v, 1, 64); v += __shfl_xor(v, 2, 64);
      v += __shfl_xor(v, 4, 64); v += __shfl_xor(v, 8, 64);
      if (m == 0) scaleE[rbase + w * 32 + rt * 16 + kq * 4 + j] = v;
    }
}

// aggAcc/deg -> nodeA[:,128:256] bf16
__global__ __launch_bounds__(256) void k_aggfin(const float* __restrict__ aggAcc,
                                                const int* __restrict__ cnt,
                                                unsigned short* __restrict__ nodeA) {
  int idx = blockIdx.x * 256 + threadIdx.x;
  if (idx >= Nn * 128) return;
  int n = idx >> 7, ch = idx & 127;
  float inv = 1.f / fmaxf((float)cnt[n], 1.f);
  nodeA[(size_t)n * 256 + 128 + ch] = f2bf(aggAcc[idx] * inv);
}

// coord_out: contiguous CSR ranges, coalesced
__global__ __launch_bounds__(256) void k_coord(const float* __restrict__ coord,
                                               const unsigned short* __restrict__ colS,
                                               const int* __restrict__ start,
                                               const int* __restrict__ cnt,
                                               const float* __restrict__ scaleE,
                                               float* __restrict__ cout) {
  int tid = threadIdx.x;
  int lane = tid & 63;
  int n = blockIdx.x * 4 + (tid >> 6);
  if (n >= Nn) return;
  int deg = cnt[n], off = start[n];
  float cx0 = coord[n * 3 + 0], cy0 = coord[n * 3 + 1], cz0 = coord[n * 3 + 2];
  float ax = 0.f, ay = 0.f, az = 0.f;
  for (int j = lane; j < deg; j += 64) {
    int e = off + j;
    int c = colS[e];
    float s = scaleE[e];
    float tx = (cx0 - coord[c * 3 + 0]) * s;
    float ty = (cy0 - coord[c * 3 + 1]) * s;
    float tz = (cz0 - coord[c * 3 + 2]) * s;
    ax += fminf(fmaxf(tx, -100.f), 100.f);
    ay += fminf(fmaxf(ty, -100.f), 100.f);
    az += fminf(fmaxf(tz, -100.f), 100.f);
  }
#pragma unroll
  for (int d = 32; d; d >>= 1) {
    ax += __shfl_xor(ax, d, 64);
    ay += __shfl_xor(ay, d, 64);
    az += __shfl_xor(az, d, 64);
  }
  if (lane == 0) {
    float inv = 1.f / fmaxf((float)deg, 1.f);
    cout[n * 3 + 0] = cx0 + ax * inv;
    cout[n * 3 + 1] = cy0 + ay * inv;
    cout[n * 3 + 2] = cz0 + az * inv;
  }
}

// ---------------- launcher ----------------

extern "C" void kernel_launch(void* const* d_in, const int* in_sizes, int n_in, void* d_out,
                              int out_size, void* d_ws, size_t ws_size, hipStream_t stream) {
  (void)in_sizes; (void)n_in; (void)out_size; (void)ws_size;
  const float* h = (const float*)d_in[0];
  const float* coord = (const float*)d_in[1];
  const int* eidx = (const int*)d_in[2];
  const int* row = eidx;
  const int* col = eidx + En;
  const float* e_w1 = (const float*)d_in[3];
  const float* e_b1 = (const float*)d_in[4];
  const float* e_g1 = (const float*)d_in[5];
  const float* e_be1 = (const float*)d_in[6];
  const float* e_w2 = (const float*)d_in[7];
  const float* e_b2 = (const float*)d_in[8];
  const float* e_g2 = (const float*)d_in[9];
  const float* e_be2 = (const float*)d_in[10];
  const float* n_w1 = (const float*)d_in[11];
  const float* n_b1 = (const float*)d_in[12];
  const float* n_g1 = (const float*)d_in[13];
  const float* n_be1 = (const float*)d_in[14];
  const float* n_w2 = (const float*)d_in[15];
  const float* n_b2 = (const float*)d_in[16];
  const float* c_w1 = (const float*)d_in[17];
  const float* c_b1 = (const float*)d_in[18];
  const float* c_g1 = (const float*)d_in[19];
  const float* c_be1 = (const float*)d_in[20];
  const float* c_w2 = (const float*)d_in[21];

  char* base = (char*)d_ws;
  size_t off = 0;
  auto alloc = [&](size_t bytes) -> void* {
    void* p = base + off;
    off = (off + bytes + 255) & ~(size_t)255;
    return p;
  };
  // Workspace budget: ~263.5 MB (round-3 proven footprint).
  unsigned short* t = (unsigned short*)alloc((size_t)En * 128 * 2);      // t2, later t4
  unsigned short* nodeA = (unsigned short*)alloc((size_t)Nn * 256 * 2);  // [h | agg] bf16
  unsigned short* hWr = (unsigned short*)alloc((size_t)Nn * 128 * 2);
  unsigned short* hWc = (unsigned short*)alloc((size_t)Nn * 128 * 2);
  float* aggAcc = (float*)hWr;  // alias: hWr+hWc contiguous 25.6MB, dead after k_egemm2
  float* scaleE = (float*)alloc((size_t)En * 4);
  float* radS = scaleE;  // alias: radS dead before scaleE is first written (k_cscale)
  unsigned short* rowS = (unsigned short*)alloc((size_t)En * 2);
  unsigned short* colS = (unsigned short*)alloc((size_t)En * 2);
  int* cnt = (int*)alloc((size_t)Nn * 4);
  int* startp = (int*)alloc((size_t)Nn * 4);
  int* cursor = (int*)alloc((size_t)Nn * 4);
  float* statS = (float*)alloc(4 * NSLOT * 128 * 4);
  float* statQ = (float*)alloc(4 * NSLOT * 128 * 4);
  float* bnS = (float*)alloc(4 * 128 * 4);
  float* bnSh = (float*)alloc(4 * 128 * 4);
  unsigned short* w1a = (unsigned short*)alloc(128 * 128 * 2);
  unsigned short* w1b = (unsigned short*)alloc(128 * 128 * 2);
  unsigned short* w2b = (unsigned short*)alloc(128 * 128 * 2);
  unsigned short* c1b = (unsigned short*)alloc(128 * 128 * 2);
  unsigned short* n1b = (unsigned short*)alloc(128 * 256 * 2);
  unsigned short* n2b = (unsigned short*)alloc(128 * 128 * 2);
  float* wlast = (float*)alloc(128 * 4);

  hipMemsetAsync(cnt, 0, (size_t)Nn * 4, stream);
  hipMemsetAsync(statS, 0, 4 * NSLOT * 128 * 4, stream);
  hipMemsetAsync(statQ, 0, 4 * NSLOT * 128 * 4, stream);

  // prep
  k_prep_h<<<(Nn * 128 + 255) / 256, 256, 0, stream>>>(h, nodeA);
  k_prep_w<<<(128 * 128 + 255) / 256, 256, 0, stream>>>(e_w1, w1a, 257, 0, 7, 128 * 128);
  k_prep_w<<<(128 * 128 + 255) / 256, 256, 0, stream>>>(e_w1, w1b, 257, 128, 7, 128 * 128);
  k_prep_w<<<(128 * 128 + 255) / 256, 256, 0, stream>>>(e_w2, w2b, 128, 0, 7, 128 * 128);
  k_prep_w<<<(128 * 128 + 255) / 256, 256, 0, stream>>>(c_w1, c1b, 128, 0, 7, 128 * 128);
  k_prep_w<<<(128 * 256 + 255) / 256, 256, 0, stream>>>(n_w1, n1b, 256, 0, 8, 128 * 256);
  k_prep_w<<<(128 * 128 + 255) / 256, 256, 0, stream>>>(n_w2, n2b, 128, 0, 7, 128 * 128);
  k_wlast<<<1, 128, 0, stream>>>(e_w1, wlast);

  // CSR sort
  k_count<<<En / 256, 256, 0, stream>>>(row, cnt);
  k_scan<<<1, 1024, 0, stream>>>(cnt, startp, cursor, Nn);
  k_fill<<<En / 256, 256, 0, stream>>>(row, col, cursor, rowS, colS);

  // hW partial GEMMs (bias e_b1 folded into hWr)
  const int gridN = (Nn + 127) / 128;
  k_gemmW<4, false, false, false, true><<<gridN, 256, 0, stream>>>(
      nodeA, 256, w1a, e_b1, nullptr, nullptr, hWr, nullptr, nullptr, nullptr, nullptr, Nn);
  k_gemmW<4, false, false, false, true><<<gridN, 256, 0, stream>>>(
      nodeA, 256, w1b, nullptr, nullptr, nullptr, hWc, nullptr, nullptr, nullptr, nullptr, Nn);

  // bn1 stats over virtual t1 + radS
  const int per_wave = (En + 5119) / 5120;  // 1280 blocks * 4 waves
  k_stats1<<<1280, 256, 0, stream>>>(hWr, hWc, coord, rowS, colS, wlast, radS,
                                     statS + 0 * NSLOT * 128, statQ + 0 * NSLOT * 128, per_wave);
  k_fin<<<1, 128, 0, stream>>>(statS + 0 * NSLOT * 128, statQ + 0 * NSLOT * 128, e_g1, e_be1,
                               1.f / En, bnS + 0, bnSh + 0);

  // edge layer 2: t2 + bn2 stats (slot 1)
  k_egemm2<<<En / 128, 256, 0, stream>>>(hWr, hWc, radS, rowS, colS, w2b, e_b2, wlast, bnS + 0,
                                         bnSh + 0, t, statS + 1 * NSLOT * 128,
                                         statQ + 1 * NSLOT * 128);
  k_fin<<<1, 128, 0, stream>>>(statS + 1 * NSLOT * 128, statQ + 1 * NSLOT * 128, e_g2, e_be2,
                               1.f / En, bnS + 128, bnSh + 128);

  // hWr/hWc now dead -> init aggAcc (aliases them)
  hipMemsetAsync(aggAcc, 0, (size_t)Nn * 128 * 4, stream);

  // Pass A: aggregation of Y + bn3 stats (slot 2), single read of t
  k_caggstats<<<En / 128, 256, 0, stream>>>(t, c1b, c_b1, bnS + 128, bnSh + 128, rowS, aggAcc,
                                            statS + 2 * NSLOT * 128, statQ + 2 * NSLOT * 128);
  k_fin<<<1, 128, 0, stream>>>(statS + 2 * NSLOT * 128, statQ + 2 * NSLOT * 128, c_g1, c_be1,
                               1.f / En, bnS + 256, bnSh + 256);

  // Pass B: coord-l1 GEMM + scale dot -> scaleE (radS dead; scaleE written now)
  k_cscale<<<En / 128, 256, 0, stream>>>(t, c1b, c_b1, bnS + 128, bnSh + 128, bnS + 256,
                                         bnSh + 256, c_w2, scaleE);
  k_aggfin<<<(Nn * 128 + 255) / 256, 256, 0, stream>>>(aggAcc, cnt, nodeA);

  float* hout = (float*)d_out;
  float* cout = hout + (size_t)Nn * 128;
  k_coord<<<(Nn + 3) / 4, 256, 0, stream>>>(coord, colS, startp, cnt, scaleE, cout);

  // node MLP: l1 (stats slot 3) -> t4 in t; l2 fp32 residual out
  k_gemmW<8, false, true, false, true><<<gridN, 256, 0, stream>>>(
      nodeA, 256, n1b, n_b1, nullptr, nullptr, t, statS + 3 * NSLOT * 128,
      statQ + 3 * NSLOT * 128, nullptr, nullptr, Nn);
  k_fin<<<1, 128, 0, stream>>>(statS + 3 * NSLOT * 128, statQ + 3 * NSLOT * 128, n_g1, n_be1,
                               1.f / Nn, bnS + 384, bnSh + 384);
  k_gemmW<4, true, false, true, true><<<gridN, 256, 0, stream>>>(
      t, 128, n2b, n_b2, bnS + 384, bnSh + 384, nullptr, nullptr, nullptr, h, hout, Nn);
}

// Round 8
// 794.399 us; speedup vs baseline: 1.2255x; 1.1176x over previous
//
#include <hip/hip_runtime.h>

#define Nn 50000
#define En 800000
#define NSLOT 64

typedef __attribute__((ext_vector_type(8))) short short8;
typedef __attribute__((ext_vector_type(4))) float f32x4;

union U8 { uint4 u4; unsigned short us[8]; short8 s8; };

static __device__ __forceinline__ float bf2f(unsigned int lo16) {
  return __uint_as_float(lo16 << 16);
}
static __device__ __forceinline__ unsigned short f2bf(float f) {
  unsigned int x = __float_as_uint(f);
  return (unsigned short)((x + 0x7FFFu + ((x >> 16) & 1u)) >> 16);
}

// ---------------- prep kernels ----------------

__global__ __launch_bounds__(256) void k_prep_h(const float* __restrict__ h,
                                                unsigned short* __restrict__ nodeA) {
  int idx = blockIdx.x * 256 + threadIdx.x;
  if (idx >= Nn * 128) return;
  int n = idx >> 7, k = idx & 127;
  nodeA[(size_t)n * 256 + k] = f2bf(h[idx]);
}

// weight fp32 [128][Ksrc] cols [koff, koff+2^kshift) -> bf16 [128][2^kshift]
__global__ __launch_bounds__(256) void k_prep_w(const float* __restrict__ src,
                                                unsigned short* __restrict__ dst, int Ksrc,
                                                int koff, int kshift, int total) {
  int idx = blockIdx.x * 256 + threadIdx.x;
  if (idx >= total) return;
  int n = idx >> kshift;
  int k = idx & ((1 << kshift) - 1);
  dst[idx] = f2bf(src[n * Ksrc + koff + k]);
}

__global__ void k_wlast(const float* __restrict__ e_w1, float* __restrict__ wlast) {
  int t = threadIdx.x;
  if (t < 128) wlast[t] = e_w1[t * 257 + 256];
}

// ---------------- CSR build (edges sorted by row; node ids fit u16) ----------------

__global__ __launch_bounds__(256) void k_count(const int* __restrict__ row, int* __restrict__ cnt) {
  int e = blockIdx.x * 256 + threadIdx.x;
  atomicAdd(&cnt[row[e]], 1);
}

__global__ __launch_bounds__(256) void k_fill(const int* __restrict__ row,
                                              const int* __restrict__ col,
                                              int* __restrict__ cursor,
                                              unsigned short* __restrict__ rowS,
                                              unsigned short* __restrict__ colS) {
  int e = blockIdx.x * 256 + threadIdx.x;
  int r = row[e];
  int pos = atomicAdd(&cursor[r], 1);
  rowS[pos] = (unsigned short)r;
  colS[pos] = (unsigned short)col[e];
}

__global__ __launch_bounds__(1024) void k_scan(const int* __restrict__ cnt, int* __restrict__ start,
                                               int* __restrict__ cursor, int n) {
  __shared__ int wsum[16];
  __shared__ int carry;
  int tid = threadIdx.x, lane = tid & 63, wid = tid >> 6;
  if (tid == 0) carry = 0;
  __syncthreads();
  for (int base = 0; base < n; base += 1024) {
    int i = base + tid;
    int v = (i < n) ? cnt[i] : 0;
    int x = v;
#pragma unroll
    for (int d = 1; d < 64; d <<= 1) {
      int y = __shfl_up(x, d, 64);
      if (lane >= d) x += y;
    }
    if (lane == 63) wsum[wid] = x;
    __syncthreads();
    if (wid == 0) {
      int s = (lane < 16) ? wsum[lane] : 0;
#pragma unroll
      for (int d = 1; d < 16; d <<= 1) {
        int y = __shfl_up(s, d, 64);
        if (lane >= d) s += y;
      }
      if (lane < 16) wsum[lane] = s;
    }
    __syncthreads();
    int c0 = carry;
    int waveoff = (wid > 0) ? wsum[wid - 1] : 0;
    int incl = c0 + waveoff + x;
    if (i < n) {
      start[i] = incl - v;
      cursor[i] = incl - v;
    }
    __syncthreads();
    if (tid == 1023) carry = incl;
    __syncthreads();
  }
}

// ---------------- BN finalize ----------------

__global__ void k_fin(const float* __restrict__ statS, const float* __restrict__ statQ,
                      const float* __restrict__ g, const float* __restrict__ be, float invR,
                      float* __restrict__ bnS, float* __restrict__ bnSh) {
  int c = threadIdx.x;
  if (c >= 128) return;
  float s = 0.f, q = 0.f;
  for (int k = 0; k < NSLOT; ++k) {
    s += statS[k * 128 + c];
    q += statQ[k * 128 + c];
  }
  float mean = s * invR;
  float var = fmaxf(q * invR - mean * mean, 0.f);
  float rs = rsqrtf(var + 1e-5f);
  float sc = g[c] * rs;
  bnS[c] = sc;
  bnSh[c] = be[c] - mean * sc;
}

// ---------------- generic MFMA GEMM with W in LDS ----------------
template <int KSTEPS, bool BN_A, bool STATS, bool FP32OUT, bool STORE>
__global__ __launch_bounds__(256) void k_gemmW(
    const unsigned short* __restrict__ A, int Astride,
    const unsigned short* __restrict__ W, const float* __restrict__ bias,
    const float* __restrict__ bnS, const float* __restrict__ bnSh,
    unsigned short* __restrict__ outb, float* __restrict__ statS, float* __restrict__ statQ,
    const float* __restrict__ hres, float* __restrict__ outf, int R) {
  constexpr int K = KSTEPS * 32;
  constexpr int WST = K + 8;
  constexpr int SEGS = K / 8;
  __shared__ __align__(16) unsigned short smem[128 * WST];
  __shared__ float ssum[4][128], ssq[4][128];
  int tid = threadIdx.x;
  int w = tid >> 6, lane = tid & 63, m = lane & 15, kq = lane >> 4;
  int rbase = blockIdx.x * 128;
#pragma unroll
  for (int it = 0; it < SEGS / 2; ++it) {
    int idx = it * 256 + tid;
    int n = idx / SEGS, seg = idx % SEGS;
    uint4 v = *(const uint4*)(W + (size_t)n * K + seg * 8);
    *(uint4*)(smem + n * WST + seg * 8) = v;
  }
  __syncthreads();
  int row0 = rbase + w * 32 + m;
  int rc0 = min(row0, R - 1);
  int rc1 = min(row0 + 16, R - 1);
  f32x4 acc[2][8];
#pragma unroll
  for (int rt = 0; rt < 2; ++rt)
#pragma unroll
    for (int c = 0; c < 8; ++c) acc[rt][c] = (f32x4){0.f, 0.f, 0.f, 0.f};
#pragma unroll
  for (int ks = 0; ks < KSTEPS; ++ks) {
    int k0 = ks * 32 + kq * 8;
    U8 ua0, ua1;
    ua0.u4 = *(const uint4*)(A + (size_t)rc0 * Astride + k0);
    ua1.u4 = *(const uint4*)(A + (size_t)rc1 * Astride + k0);
    if (BN_A) {
      const float4* sp = (const float4*)(bnS + k0);
      const float4* hp = (const float4*)(bnSh + k0);
      float4 s0 = sp[0], s1 = sp[1], h0 = hp[0], h1 = hp[1];
      float sv[8] = {s0.x, s0.y, s0.z, s0.w, s1.x, s1.y, s1.z, s1.w};
      float hv[8] = {h0.x, h0.y, h0.z, h0.w, h1.x, h1.y, h1.z, h1.w};
#pragma unroll
      for (int j = 0; j < 8; ++j) {
        ua0.us[j] = f2bf(fmaxf(bf2f(ua0.us[j]) * sv[j] + hv[j], 0.f));
        ua1.us[j] = f2bf(fmaxf(bf2f(ua1.us[j]) * sv[j] + hv[j], 0.f));
      }
    }
#pragma unroll
    for (int c = 0; c < 8; ++c) {
      U8 ub;
      ub.u4 = *(const uint4*)(smem + (c * 16 + m) * WST + k0);
      acc[0][c] = __builtin_amdgcn_mfma_f32_16x16x32_bf16(ua0.s8, ub.s8, acc[0][c], 0, 0, 0);
      acc[1][c] = __builtin_amdgcn_mfma_f32_16x16x32_bf16(ua1.s8, ub.s8, acc[1][c], 0, 0, 0);
    }
  }
  if constexpr (FP32OUT) {
#pragma unroll
    for (int rt = 0; rt < 2; ++rt)
#pragma unroll
      for (int c = 0; c < 8; ++c) {
        int n = c * 16 + m;
        float bn_ = bias[n];
#pragma unroll
        for (int j = 0; j < 4; ++j) {
          int rr = rbase + w * 32 + rt * 16 + kq * 4 + j;
          if (rr < R) {
            size_t o = (size_t)rr * 128 + n;
            outf[o] = acc[rt][c][j] + bn_ + hres[o];
          }
        }
      }
  } else {
    if constexpr (STORE) __syncthreads();
    unsigned short* tile = smem;  // reuse as [128][136]
#pragma unroll
    for (int c = 0; c < 8; ++c) {
      int n = c * 16 + m;
      float bn_ = bias ? bias[n] : 0.f;
      float s = 0.f, q = 0.f;
#pragma unroll
      for (int rt = 0; rt < 2; ++rt)
#pragma unroll
        for (int j = 0; j < 4; ++j) {
          int lr = w * 32 + rt * 16 + kq * 4 + j;
          float v = acc[rt][c][j] + bn_;
          if (STORE) tile[lr * 136 + n] = f2bf(v);
          if (STATS) {
            float sv = (rbase + lr < R) ? v : 0.f;
            s += sv;
            q = fmaf(sv, sv, q);
          }
        }
      if (STATS) {
        s += __shfl_xor(s, 16, 64); s += __shfl_xor(s, 32, 64);
        q += __shfl_xor(q, 16, 64); q += __shfl_xor(q, 32, 64);
        if (kq == 0) { ssum[w][n] = s; ssq[w][n] = q; }
      }
    }
    if constexpr (STORE) {
      __syncthreads();
      const uint4* tl = (const uint4*)tile;
#pragma unroll
      for (int u = 0; u < 8; ++u) {
        int idx = u * 256 + tid;
        int rr = idx >> 4, seg = idx & 15;
        if (rbase + rr < R)
          *(uint4*)(outb + (size_t)(rbase + rr) * 128 + seg * 8) = tl[rr * 17 + seg];
      }
    }
    if (STATS) {
      __syncthreads();
      if (tid < 128) {
        float s = ssum[0][tid] + ssum[1][tid] + ssum[2][tid] + ssum[3][tid];
        float q = ssq[0][tid] + ssq[1][tid] + ssq[2][tid] + ssq[3][tid];
        int slot = blockIdx.x & (NSLOT - 1);
        atomicAdd(&statS[slot * 128 + tid], s);
        atomicAdd(&statQ[slot * 128 + tid], q);
      }
    }
  }
}

// ---------------- bn1 stats over virtual t1 (no materialization) + radS ----------------
// per_wave is even and En is even -> every wave's range has even length
__global__ __launch_bounds__(256) void k_stats1(
    const unsigned short* __restrict__ hWr, const unsigned short* __restrict__ hWc,
    const float* __restrict__ coord, const unsigned short* __restrict__ rowS,
    const unsigned short* __restrict__ colS, const float* __restrict__ wlast,
    float* __restrict__ radS, float* __restrict__ statS, float* __restrict__ statQ,
    int per_wave) {
  int tid = threadIdx.x, lane = tid & 63;
  int wid = blockIdx.x * 4 + (tid >> 6);
  int e0 = wid * per_wave;
  int e1 = min(e0 + per_wave, En);
  int c2 = lane * 2;
  float wl0 = wlast[c2], wl1 = wlast[c2 + 1];
  float s0 = 0.f, s1 = 0.f, q0 = 0.f, q1 = 0.f;
  for (int e = e0; e < e1; e += 2) {
    int ra = rowS[e], ca = colS[e];
    int rb = rowS[e + 1], cb = colS[e + 1];
    float ax = coord[ra * 3 + 0] - coord[ca * 3 + 0];
    float ay = coord[ra * 3 + 1] - coord[ca * 3 + 1];
    float az = coord[ra * 3 + 2] - coord[ca * 3 + 2];
    float bx = coord[rb * 3 + 0] - coord[cb * 3 + 0];
    float by = coord[rb * 3 + 1] - coord[cb * 3 + 1];
    float bz = coord[rb * 3 + 2] - coord[cb * 3 + 2];
    float rada = ax * ax + ay * ay + az * az;
    float radb = bx * bx + by * by + bz * bz;
    if (lane == 0) {
      radS[e] = rada;
      radS[e + 1] = radb;
    }
    unsigned int uar = *(const unsigned int*)(hWr + (size_t)ra * 128 + c2);
    unsigned int uac = *(const unsigned int*)(hWc + (size_t)ca * 128 + c2);
    unsigned int ubr = *(const unsigned int*)(hWr + (size_t)rb * 128 + c2);
    unsigned int ubc = *(const unsigned int*)(hWc + (size_t)cb * 128 + c2);
    float va0 = bf2f(uar & 0xFFFFu) + bf2f(uac & 0xFFFFu) + rada * wl0;
    float va1 = bf2f(uar >> 16) + bf2f(uac >> 16) + rada * wl1;
    float vb0 = bf2f(ubr & 0xFFFFu) + bf2f(ubc & 0xFFFFu) + radb * wl0;
    float vb1 = bf2f(ubr >> 16) + bf2f(ubc >> 16) + radb * wl1;
    s0 += va0 + vb0;
    s1 += va1 + vb1;
    q0 = fmaf(va0, va0, q0); q0 = fmaf(vb0, vb0, q0);
    q1 = fmaf(va1, va1, q1); q1 = fmaf(vb1, vb1, q1);
  }
  int slot = wid & (NSLOT - 1);
  atomicAdd(&statS[slot * 128 + c2], s0);
  atomicAdd(&statS[slot * 128 + c2 + 1], s1);
  atomicAdd(&statQ[slot * 128 + c2], q0);
  atomicAdd(&statQ[slot * 128 + c2 + 1], q1);
}

// ---------------- edge layer 2 GEMM, A recomputed from hWr/hWc/radS ----------------
__global__ __launch_bounds__(256) void k_egemm2(
    const unsigned short* __restrict__ hWr, const unsigned short* __restrict__ hWc,
    const float* __restrict__ radS, const unsigned short* __restrict__ rowS,
    const unsigned short* __restrict__ colS, const unsigned short* __restrict__ W,
    const float* __restrict__ bias, const float* __restrict__ wlast,
    const float* __restrict__ bnS1, const float* __restrict__ bnSh1,
    unsigned short* __restrict__ outb, float* __restrict__ statS, float* __restrict__ statQ) {
  constexpr int WST = 136;
  __shared__ __align__(16) unsigned short smem[128 * WST];
  __shared__ float ssum[4][128], ssq[4][128];
  int tid = threadIdx.x;
  int w = tid >> 6, lane = tid & 63, m = lane & 15, kq = lane >> 4;
  int rbase = blockIdx.x * 128;
#pragma unroll
  for (int it = 0; it < 8; ++it) {
    int idx = it * 256 + tid;
    int n = idx >> 4, seg = idx & 15;
    uint4 v = *(const uint4*)(W + (size_t)n * 128 + seg * 8);
    *(uint4*)(smem + n * WST + seg * 8) = v;
  }
  int rc0 = rbase + w * 32 + m, rc1 = rc0 + 16;
  int r0 = rowS[rc0], c0 = colS[rc0];
  int r1 = rowS[rc1], c1 = colS[rc1];
  float rad0 = radS[rc0], rad1 = radS[rc1];
  __syncthreads();
  f32x4 acc[2][8];
#pragma unroll
  for (int rt = 0; rt < 2; ++rt)
#pragma unroll
    for (int c = 0; c < 8; ++c) acc[rt][c] = (f32x4){0.f, 0.f, 0.f, 0.f};
#pragma unroll
  for (int ks = 0; ks < 4; ++ks) {
    int k0 = ks * 32 + kq * 8;
    U8 a0r, a0c, a1r, a1c;
    a0r.u4 = *(const uint4*)(hWr + (size_t)r0 * 128 + k0);
    a0c.u4 = *(const uint4*)(hWc + (size_t)c0 * 128 + k0);
    a1r.u4 = *(const uint4*)(hWr + (size_t)r1 * 128 + k0);
    a1c.u4 = *(const uint4*)(hWc + (size_t)c1 * 128 + k0);
    const float4* wp = (const float4*)(wlast + k0);
    const float4* sp = (const float4*)(bnS1 + k0);
    const float4* hp = (const float4*)(bnSh1 + k0);
    float4 w0 = wp[0], w1 = wp[1], sA = sp[0], sB = sp[1], hA = hp[0], hB = hp[1];
    float wv[8] = {w0.x, w0.y, w0.z, w0.w, w1.x, w1.y, w1.z, w1.w};
    float sv[8] = {sA.x, sA.y, sA.z, sA.w, sB.x, sB.y, sB.z, sB.w};
    float hv[8] = {hA.x, hA.y, hA.z, hA.w, hB.x, hB.y, hB.z, hB.w};
    U8 ua0, ua1;
#pragma unroll
    for (int j = 0; j < 8; ++j) {
      float v0 = bf2f(a0r.us[j]) + bf2f(a0c.us[j]) + rad0 * wv[j];
      float v1 = bf2f(a1r.us[j]) + bf2f(a1c.us[j]) + rad1 * wv[j];
      ua0.us[j] = f2bf(fmaxf(v0 * sv[j] + hv[j], 0.f));
      ua1.us[j] = f2bf(fmaxf(v1 * sv[j] + hv[j], 0.f));
    }
#pragma unroll
    for (int c = 0; c < 8; ++c) {
      U8 ub;
      ub.u4 = *(const uint4*)(smem + (c * 16 + m) * WST + k0);
      acc[0][c] = __builtin_amdgcn_mfma_f32_16x16x32_bf16(ua0.s8, ub.s8, acc[0][c], 0, 0, 0);
      acc[1][c] = __builtin_amdgcn_mfma_f32_16x16x32_bf16(ua1.s8, ub.s8, acc[1][c], 0, 0, 0);
    }
  }
  __syncthreads();
  unsigned short* tile = smem;
#pragma unroll
  for (int c = 0; c < 8; ++c) {
    int n = c * 16 + m;
    float bn_ = bias[n];
    float s = 0.f, q = 0.f;
#pragma unroll
    for (int rt = 0; rt < 2; ++rt)
#pragma unroll
      for (int j = 0; j < 4; ++j) {
        int lr = w * 32 + rt * 16 + kq * 4 + j;
        float v = acc[rt][c][j] + bn_;
        tile[lr * 136 + n] = f2bf(v);
        s += v;
        q = fmaf(v, v, q);
      }
    s += __shfl_xor(s, 16, 64); s += __shfl_xor(s, 32, 64);
    q += __shfl_xor(q, 16, 64); q += __shfl_xor(q, 32, 64);
    if (kq == 0) { ssum[w][n] = s; ssq[w][n] = q; }
  }
  __syncthreads();
  const uint4* tl = (const uint4*)tile;
#pragma unroll
  for (int u = 0; u < 8; ++u) {
    int idx = u * 256 + tid;
    int rr = idx >> 4, seg = idx & 15;
    *(uint4*)(outb + (size_t)(rbase + rr) * 128 + seg * 8) = tl[rr * 17 + seg];
  }
  if (tid < 128) {
    float s = ssum[0][tid] + ssum[1][tid] + ssum[2][tid] + ssum[3][tid];
    float q = ssq[0][tid] + ssq[1][tid] + ssq[2][tid] + ssq[3][tid];
    int slot = blockIdx.x & (NSLOT - 1);
    atomicAdd(&statS[slot * 128 + tid], s);
    atomicAdd(&statQ[slot * 128 + tid], q);
  }
}

// ---------------- node aggregation over contiguous CSR rows (no atomics) ----------------
// agg[n] = mean over its contiguous sorted edges of relu(bn2(t2[e])) -> nodeA[:,128:256]
__global__ __launch_bounds__(256) void k_agg(const unsigned short* __restrict__ t,
                                             const int* __restrict__ start,
                                             const int* __restrict__ cnt,
                                             const float* __restrict__ bnS,
                                             const float* __restrict__ bnSh,
                                             unsigned short* __restrict__ nodeA) {
  int tid = threadIdx.x;
  int lane = tid & 63;
  int n = blockIdx.x * 4 + (tid >> 6);
  if (n >= Nn) return;
  int deg = cnt[n], off = start[n];
  int c2 = lane * 2;
  float s0 = bnS[c2], s1 = bnS[c2 + 1], h0 = bnSh[c2], h1 = bnSh[c2 + 1];
  float a0 = 0.f, a1 = 0.f;
  const unsigned short* p = t + (size_t)off * 128 + c2;
  for (int j = 0; j < deg; ++j) {
    unsigned int u = *(const unsigned int*)(p + (size_t)j * 128);
    a0 += fmaxf(bf2f(u & 0xFFFFu) * s0 + h0, 0.f);
    a1 += fmaxf(bf2f(u >> 16) * s1 + h1, 0.f);
  }
  float inv = 1.f / fmaxf((float)deg, 1.f);
  unsigned int o = (unsigned)f2bf(a0 * inv) | ((unsigned)f2bf(a1 * inv) << 16);
  *(unsigned int*)(nodeA + (size_t)n * 256 + 128 + c2) = o;
}

// ---------------- elementwise scale from stored t3 ----------------
// scale[e] = sum_c cw2[c]*relu(bn3(t3[e][c])); wave handles 2 consecutive edges
__global__ __launch_bounds__(256) void k_scale2(const unsigned short* __restrict__ t,
                                                const float* __restrict__ bnS3,
                                                const float* __restrict__ bnSh3,
                                                const float* __restrict__ cw2,
                                                float* __restrict__ scaleE) {
  int tid = threadIdx.x, lane = tid & 63, w = tid >> 6;
  long e = (long)blockIdx.x * 8 + w * 2;
  int c2 = lane * 2;
  float s0 = bnS3[c2], s1 = bnS3[c2 + 1];
  float h0 = bnSh3[c2], h1 = bnSh3[c2 + 1];
  float w0 = cw2[c2], w1 = cw2[c2 + 1];
  unsigned int ua = *(const unsigned int*)(t + e * 128 + c2);
  unsigned int ub = *(const unsigned int*)(t + (e + 1) * 128 + c2);
  float pa = fmaxf(bf2f(ua & 0xFFFFu) * s0 + h0, 0.f) * w0 +
             fmaxf(bf2f(ua >> 16) * s1 + h1, 0.f) * w1;
  float pb = fmaxf(bf2f(ub & 0xFFFFu) * s0 + h0, 0.f) * w0 +
             fmaxf(bf2f(ub >> 16) * s1 + h1, 0.f) * w1;
#pragma unroll
  for (int d = 32; d; d >>= 1) {
    pa += __shfl_xor(pa, d, 64);
    pb += __shfl_xor(pb, d, 64);
  }
  if (lane == 0) {
    scaleE[e] = pa;
    scaleE[e + 1] = pb;
  }
}

// coord_out: contiguous CSR ranges, coalesced
__global__ __launch_bounds__(256) void k_coord(const float* __restrict__ coord,
                                               const unsigned short* __restrict__ colS,
                                               const int* __restrict__ start,
                                               const int* __restrict__ cnt,
                                               const float* __restrict__ scaleE,
                                               float* __restrict__ cout) {
  int tid = threadIdx.x;
  int lane = tid & 63;
  int n = blockIdx.x * 4 + (tid >> 6);
  if (n >= Nn) return;
  int deg = cnt[n], off = start[n];
  float cx0 = coord[n * 3 + 0], cy0 = coord[n * 3 + 1], cz0 = coord[n * 3 + 2];
  float ax = 0.f, ay = 0.f, az = 0.f;
  for (int j = lane; j < deg; j += 64) {
    int e = off + j;
    int c = colS[e];
    float s = scaleE[e];
    float tx = (cx0 - coord[c * 3 + 0]) * s;
    float ty = (cy0 - coord[c * 3 + 1]) * s;
    float tz = (cz0 - coord[c * 3 + 2]) * s;
    ax += fminf(fmaxf(tx, -100.f), 100.f);
    ay += fminf(fmaxf(ty, -100.f), 100.f);
    az += fminf(fmaxf(tz, -100.f), 100.f);
  }
#pragma unroll
  for (int d = 32; d; d >>= 1) {
    ax += __shfl_xor(ax, d, 64);
    ay += __shfl_xor(ay, d, 64);
    az += __shfl_xor(az, d, 64);
  }
  if (lane == 0) {
    float inv = 1.f / fmaxf((float)deg, 1.f);
    cout[n * 3 + 0] = cx0 + ax * inv;
    cout[n * 3 + 1] = cy0 + ay * inv;
    cout[n * 3 + 2] = cz0 + az * inv;
  }
}

// ---------------- launcher ----------------

extern "C" void kernel_launch(void* const* d_in, const int* in_sizes, int n_in, void* d_out,
                              int out_size, void* d_ws, size_t ws_size, hipStream_t stream) {
  (void)in_sizes; (void)n_in; (void)out_size; (void)ws_size;
  const float* h = (const float*)d_in[0];
  const float* coord = (const float*)d_in[1];
  const int* eidx = (const int*)d_in[2];
  const int* row = eidx;
  const int* col = eidx + En;
  const float* e_w1 = (const float*)d_in[3];
  const float* e_b1 = (const float*)d_in[4];
  const float* e_g1 = (const float*)d_in[5];
  const float* e_be1 = (const float*)d_in[6];
  const float* e_w2 = (const float*)d_in[7];
  const float* e_b2 = (const float*)d_in[8];
  const float* e_g2 = (const float*)d_in[9];
  const float* e_be2 = (const float*)d_in[10];
  const float* n_w1 = (const float*)d_in[11];
  const float* n_b1 = (const float*)d_in[12];
  const float* n_g1 = (const float*)d_in[13];
  const float* n_be1 = (const float*)d_in[14];
  const float* n_w2 = (const float*)d_in[15];
  const float* n_b2 = (const float*)d_in[16];
  const float* c_w1 = (const float*)d_in[17];
  const float* c_b1 = (const float*)d_in[18];
  const float* c_g1 = (const float*)d_in[19];
  const float* c_be1 = (const float*)d_in[20];
  const float* c_w2 = (const float*)d_in[21];

  char* base = (char*)d_ws;
  size_t off = 0;
  auto alloc = [&](size_t bytes) -> void* {
    void* p = base + off;
    off = (off + bytes + 255) & ~(size_t)255;
    return p;
  };
  // Workspace budget: ~260 MB (round-3 proven footprint).
  unsigned short* t = (unsigned short*)alloc((size_t)En * 128 * 2);      // t2, then t3, then t4
  unsigned short* nodeA = (unsigned short*)alloc((size_t)Nn * 256 * 2);  // [h | agg] bf16
  unsigned short* hWr = (unsigned short*)alloc((size_t)Nn * 128 * 2);
  unsigned short* hWc = (unsigned short*)alloc((size_t)Nn * 128 * 2);
  float* scaleE = (float*)alloc((size_t)En * 4);
  float* radS = scaleE;  // alias: radS dead (after k_egemm2) before scaleE is written (k_scale2)
  unsigned short* rowS = (unsigned short*)alloc((size_t)En * 2);
  unsigned short* colS = (unsigned short*)alloc((size_t)En * 2);
  int* cnt = (int*)alloc((size_t)Nn * 4);
  int* startp = (int*)alloc((size_t)Nn * 4);
  int* cursor = (int*)alloc((size_t)Nn * 4);
  float* statS = (float*)alloc(4 * NSLOT * 128 * 4);
  float* statQ = (float*)alloc(4 * NSLOT * 128 * 4);
  float* bnS = (float*)alloc(4 * 128 * 4);
  float* bnSh = (float*)alloc(4 * 128 * 4);
  unsigned short* w1a = (unsigned short*)alloc(128 * 128 * 2);
  unsigned short* w1b = (unsigned short*)alloc(128 * 128 * 2);
  unsigned short* w2b = (unsigned short*)alloc(128 * 128 * 2);
  unsigned short* c1b = (unsigned short*)alloc(128 * 128 * 2);
  unsigned short* n1b = (unsigned short*)alloc(128 * 256 * 2);
  unsigned short* n2b = (unsigned short*)alloc(128 * 128 * 2);
  float* wlast = (float*)alloc(128 * 4);

  hipMemsetAsync(cnt, 0, (size_t)Nn * 4, stream);
  hipMemsetAsync(statS, 0, 4 * NSLOT * 128 * 4, stream);
  hipMemsetAsync(statQ, 0, 4 * NSLOT * 128 * 4, stream);

  // prep
  k_prep_h<<<(Nn * 128 + 255) / 256, 256, 0, stream>>>(h, nodeA);
  k_prep_w<<<(128 * 128 + 255) / 256, 256, 0, stream>>>(e_w1, w1a, 257, 0, 7, 128 * 128);
  k_prep_w<<<(128 * 128 + 255) / 256, 256, 0, stream>>>(e_w1, w1b, 257, 128, 7, 128 * 128);
  k_prep_w<<<(128 * 128 + 255) / 256, 256, 0, stream>>>(e_w2, w2b, 128, 0, 7, 128 * 128);
  k_prep_w<<<(128 * 128 + 255) / 256, 256, 0, stream>>>(c_w1, c1b, 128, 0, 7, 128 * 128);
  k_prep_w<<<(128 * 256 + 255) / 256, 256, 0, stream>>>(n_w1, n1b, 256, 0, 8, 128 * 256);
  k_prep_w<<<(128 * 128 + 255) / 256, 256, 0, stream>>>(n_w2, n2b, 128, 0, 7, 128 * 128);
  k_wlast<<<1, 128, 0, stream>>>(e_w1, wlast);

  // CSR sort
  k_count<<<En / 256, 256, 0, stream>>>(row, cnt);
  k_scan<<<1, 1024, 0, stream>>>(cnt, startp, cursor, Nn);
  k_fill<<<En / 256, 256, 0, stream>>>(row, col, cursor, rowS, colS);

  // hW partial GEMMs (bias e_b1 folded into hWr)
  const int gridN = (Nn + 127) / 128;
  k_gemmW<4, false, false, false, true><<<gridN, 256, 0, stream>>>(
      nodeA, 256, w1a, e_b1, nullptr, nullptr, hWr, nullptr, nullptr, nullptr, nullptr, Nn);
  k_gemmW<4, false, false, false, true><<<gridN, 256, 0, stream>>>(
      nodeA, 256, w1b, nullptr, nullptr, nullptr, hWc, nullptr, nullptr, nullptr, nullptr, Nn);

  // bn1 stats over virtual t1 + radS (per_wave even for the 2-edge unroll)
  const int per_wave = ((En / 2 + 5119) / 5120) * 2;  // 1280 blocks * 4 waves
  k_stats1<<<1280, 256, 0, stream>>>(hWr, hWc, coord, rowS, colS, wlast, radS,
                                     statS + 0 * NSLOT * 128, statQ + 0 * NSLOT * 128, per_wave);
  k_fin<<<1, 128, 0, stream>>>(statS + 0 * NSLOT * 128, statQ + 0 * NSLOT * 128, e_g1, e_be1,
                               1.f / En, bnS + 0, bnSh + 0);

  // edge layer 2: t2 + bn2 stats (slot 1)
  k_egemm2<<<En / 128, 256, 0, stream>>>(hWr, hWc, radS, rowS, colS, w2b, e_b2, wlast, bnS + 0,
                                         bnSh + 0, t, statS + 1 * NSLOT * 128,
                                         statQ + 1 * NSLOT * 128);
  k_fin<<<1, 128, 0, stream>>>(statS + 1 * NSLOT * 128, statQ + 1 * NSLOT * 128, e_g2, e_be2,
                               1.f / En, bnS + 128, bnSh + 128);

  // node aggregation from contiguous t2 rows (no atomics), before t is overwritten
  k_agg<<<(Nn + 3) / 4, 256, 0, stream>>>(t, startp, cnt, bnS + 128, bnSh + 128, nodeA);

  // coord-l1 GEMM once: t3 = relu(bn2(t2))@c_w1^T + c_b1, in-place t -> t, bn3 stats (slot 2)
  k_gemmW<4, true, true, false, true><<<En / 128, 256, 0, stream>>>(
      t, 128, c1b, c_b1, bnS + 128, bnSh + 128, t, statS + 2 * NSLOT * 128,
      statQ + 2 * NSLOT * 128, nullptr, nullptr, En);
  k_fin<<<1, 128, 0, stream>>>(statS + 2 * NSLOT * 128, statQ + 2 * NSLOT * 128, c_g1, c_be1,
                               1.f / En, bnS + 256, bnSh + 256);

  // elementwise scale from stored t3
  k_scale2<<<En / 8, 256, 0, stream>>>(t, bnS + 256, bnSh + 256, c_w2, scaleE);

  float* hout = (float*)d_out;
  float* cout = hout + (size_t)Nn * 128;
  k_coord<<<(Nn + 3) / 4, 256, 0, stream>>>(coord, colS, startp, cnt, scaleE, cout);

  // node MLP: l1 (stats slot 3) -> t4 in t (overwrites t3, after k_scale2); l2 fp32 out
  k_gemmW<8, false, true, false, true><<<gridN, 256, 0, stream>>>(
      nodeA, 256, n1b, n_b1, nullptr, nullptr, t, statS + 3 * NSLOT * 128,
      statQ + 3 * NSLOT * 128, nullptr, nullptr, Nn);
  k_fin<<<1, 128, 0, stream>>>(statS + 3 * NSLOT * 128, statQ + 3 * NSLOT * 128, n_g1, n_be1,
                               1.f / Nn, bnS + 384, bnSh + 384);
  k_gemmW<4, true, false, true, true><<<gridN, 256, 0, stream>>>(
      t, 128, n2b, n_b2, bnS + 384, bnSh + 384, nullptr, nullptr, nullptr, h, hout, Nn);
}